// Round 1
// baseline (1825.870 us; speedup 1.0000x reference)
//
#include <hip/hip_runtime.h>
#include <hip/hip_bf16.h>
#include <float.h>

#define N_NODES 8192
#define NEDGE   524288
#define IND     128
#define HID     256
#define OUTD    128
#define NHEAD   4
#define HD      64

__device__ __forceinline__ float sigmoidf_(float x) { return 1.0f / (1.0f + expf(-x)); }

// ---------------- generic C[M,N] = A[M,K] * W[N,K]^T + bias ----------------
__global__ __launch_bounds__(256) void gemm_bias_kernel(
    const float* __restrict__ A, const float* __restrict__ W,
    const float* __restrict__ bias, float* __restrict__ C,
    int M, int Nn, int K)
{
    __shared__ float As[64][33];
    __shared__ float Ws[64][33];
    const int t  = threadIdx.x;
    const int tx = t & 15, ty = t >> 4;
    const int m0 = blockIdx.x * 64, n0 = blockIdx.y * 64;
    const int lr = t >> 2;            // 0..63 tile row
    const int lc = (t & 3) * 8;       // 8-col group

    float acc[4][4] = {};
    for (int kk = 0; kk < K; kk += 32) {
        const float* Ap = A + (size_t)(m0 + lr) * K + kk + lc;
        const float* Wp = W + (size_t)(n0 + lr) * K + kk + lc;
        float4 a0 = *(const float4*)(Ap);
        float4 a1 = *(const float4*)(Ap + 4);
        float4 w0 = *(const float4*)(Wp);
        float4 w1 = *(const float4*)(Wp + 4);
        __syncthreads();   // previous compute done before overwrite
        As[lr][lc + 0] = a0.x; As[lr][lc + 1] = a0.y; As[lr][lc + 2] = a0.z; As[lr][lc + 3] = a0.w;
        As[lr][lc + 4] = a1.x; As[lr][lc + 5] = a1.y; As[lr][lc + 6] = a1.z; As[lr][lc + 7] = a1.w;
        Ws[lr][lc + 0] = w0.x; Ws[lr][lc + 1] = w0.y; Ws[lr][lc + 2] = w0.z; Ws[lr][lc + 3] = w0.w;
        Ws[lr][lc + 4] = w1.x; Ws[lr][lc + 5] = w1.y; Ws[lr][lc + 6] = w1.z; Ws[lr][lc + 7] = w1.w;
        __syncthreads();
        #pragma unroll 8
        for (int k = 0; k < 32; ++k) {
            float a[4], w[4];
            #pragma unroll
            for (int i = 0; i < 4; ++i) a[i] = As[ty * 4 + i][k];
            #pragma unroll
            for (int j = 0; j < 4; ++j) w[j] = Ws[tx * 4 + j][k];
            #pragma unroll
            for (int i = 0; i < 4; ++i)
                #pragma unroll
                for (int j = 0; j < 4; ++j)
                    acc[i][j] += a[i] * w[j];
        }
    }
    #pragma unroll
    for (int i = 0; i < 4; ++i) {
        const int m = m0 + ty * 4 + i;
        #pragma unroll
        for (int j = 0; j < 4; ++j) {
            const int n = n0 + tx * 4 + j;
            C[(size_t)m * Nn + n] = acc[i][j] + bias[n];
        }
    }
}

// ---------------- CSR build ----------------
__global__ void hist_kernel(const int* __restrict__ ei, int* __restrict__ deg)
{
    int e = blockIdx.x * blockDim.x + threadIdx.x;
    if (e < NEDGE) atomicAdd(&deg[ei[NEDGE + e]], 1);
}

__global__ __launch_bounds__(1024) void scan_kernel(
    const int* __restrict__ deg, int* __restrict__ row_ptr, int* __restrict__ cursor)
{
    __shared__ int sh[1024];
    const int t = threadIdx.x;
    int v[8]; int s = 0;
    #pragma unroll
    for (int i = 0; i < 8; ++i) { v[i] = deg[t * 8 + i]; s += v[i]; }
    sh[t] = s; __syncthreads();
    for (int off = 1; off < 1024; off <<= 1) {
        int add = (t >= off) ? sh[t - off] : 0;
        __syncthreads();
        sh[t] += add;
        __syncthreads();
    }
    int base = sh[t] - s;   // exclusive prefix
    #pragma unroll
    for (int i = 0; i < 8; ++i) {
        row_ptr[t * 8 + i] = base;
        cursor[t * 8 + i]  = base;
        base += v[i];
    }
    if (t == 1023) row_ptr[N_NODES] = base;
}

__global__ void scatter_kernel(const int* __restrict__ ei, int* __restrict__ cursor,
                               int* __restrict__ esrc)
{
    int e = blockIdx.x * blockDim.x + threadIdx.x;
    if (e < NEDGE) {
        int d = ei[NEDGE + e];
        int p = atomicAdd(&cursor[d], 1);
        esrc[p] = ei[e];
    }
}

// ---------------- GNN layer: out[dst] = leaky(scale * sum_{src in CSR} in[src]) ----------------
__global__ __launch_bounds__(256) void aggregate_kernel(
    const float* __restrict__ hin, float* __restrict__ hout,
    const int* __restrict__ row_ptr, const int* __restrict__ esrc,
    const float* __restrict__ plas, const float* __restrict__ syn, int layer)
{
    const int b = blockIdx.x;
    const int c = threadIdx.x;
    const int st = row_ptr[b], en = row_ptr[b + 1];
    float a0 = 0.f, a1 = 0.f, a2 = 0.f, a3 = 0.f;
    int e = st;
    for (; e + 4 <= en; e += 4) {
        int s0 = esrc[e], s1 = esrc[e + 1], s2 = esrc[e + 2], s3 = esrc[e + 3];
        a0 += hin[(size_t)s0 * HID + c];
        a1 += hin[(size_t)s1 * HID + c];
        a2 += hin[(size_t)s2 * HID + c];
        a3 += hin[(size_t)s3 * HID + c];
    }
    float acc = (a0 + a1) + (a2 + a3);
    for (; e < en; ++e) acc += hin[(size_t)esrc[e] * HID + c];
    const float scale = sigmoidf_(plas[layer]) * sigmoidf_(syn[layer]);
    float x = acc * scale;
    hout[(size_t)b * HID + c] = (x > 0.f) ? x : 0.01f * x;
}

// ---------------- flash attention, fp32 vector ----------------
// qkv: [N][768]; q at col h*64, k at 256+h*64, v at 512+h*64. O: [N][256].
__global__ __launch_bounds__(256) void attn_kernel(
    const float* __restrict__ qkv, float* __restrict__ O)
{
    __shared__ float Qs[64][65];
    __shared__ float Ks[64][65];
    __shared__ float Vs[64][65];
    __shared__ float Ss[64][65];
    __shared__ float mrow[64], lrow[64], arow[64];

    const int h  = blockIdx.y;
    const int n0 = blockIdx.x * 64;
    const int t  = threadIdx.x;
    const int tx = t & 15, ty = t >> 4;
    const int lr = t >> 2;            // 0..63
    const int d0 = (t & 3) * 16;      // 16-col group

    // load Q tile (pre-scaled by 1/sqrt(64))
    {
        const float* qp = qkv + (size_t)(n0 + lr) * 768 + h * HD + d0;
        #pragma unroll
        for (int i = 0; i < 16; i += 4) {
            float4 q4 = *(const float4*)(qp + i);
            Qs[lr][d0 + i + 0] = q4.x * 0.125f;
            Qs[lr][d0 + i + 1] = q4.y * 0.125f;
            Qs[lr][d0 + i + 2] = q4.z * 0.125f;
            Qs[lr][d0 + i + 3] = q4.w * 0.125f;
        }
    }
    if (t < 64) { mrow[t] = -FLT_MAX; lrow[t] = 0.f; }
    float o[4][4] = {};
    __syncthreads();

    for (int kt = 0; kt < N_NODES / 64; ++kt) {
        __syncthreads();   // previous PV done with Ks/Vs/Ss
        {
            const int kn = kt * 64 + lr;
            const float* kp = qkv + (size_t)kn * 768 + 256 + h * HD + d0;
            const float* vp = qkv + (size_t)kn * 768 + 512 + h * HD + d0;
            #pragma unroll
            for (int i = 0; i < 16; i += 4) {
                float4 k4 = *(const float4*)(kp + i);
                float4 v4 = *(const float4*)(vp + i);
                Ks[lr][d0 + i + 0] = k4.x; Ks[lr][d0 + i + 1] = k4.y;
                Ks[lr][d0 + i + 2] = k4.z; Ks[lr][d0 + i + 3] = k4.w;
                Vs[lr][d0 + i + 0] = v4.x; Vs[lr][d0 + i + 1] = v4.y;
                Vs[lr][d0 + i + 2] = v4.z; Vs[lr][d0 + i + 3] = v4.w;
            }
        }
        __syncthreads();

        // S tile: 4x4 per thread over d=64
        {
            float s[4][4] = {};
            #pragma unroll 4
            for (int d = 0; d < HD; ++d) {
                float a[4], w[4];
                #pragma unroll
                for (int i = 0; i < 4; ++i) a[i] = Qs[ty * 4 + i][d];
                #pragma unroll
                for (int j = 0; j < 4; ++j) w[j] = Ks[tx * 4 + j][d];
                #pragma unroll
                for (int i = 0; i < 4; ++i)
                    #pragma unroll
                    for (int j = 0; j < 4; ++j)
                        s[i][j] += a[i] * w[j];
            }
            #pragma unroll
            for (int i = 0; i < 4; ++i)
                #pragma unroll
                for (int j = 0; j < 4; ++j)
                    Ss[ty * 4 + i][tx * 4 + j] = s[i][j];
        }
        __syncthreads();

        // online softmax row phase: 4 threads per row
        {
            const int r  = t >> 2;
            const int c0 = (t & 3) * 16;
            float mx = -FLT_MAX;
            #pragma unroll
            for (int i = 0; i < 16; ++i) mx = fmaxf(mx, Ss[r][c0 + i]);
            mx = fmaxf(mx, __shfl_xor(mx, 1));
            mx = fmaxf(mx, __shfl_xor(mx, 2));
            const float m_old = mrow[r];
            const float m_new = fmaxf(m_old, mx);
            float sum = 0.f;
            #pragma unroll
            for (int i = 0; i < 16; ++i) {
                float p = __expf(Ss[r][c0 + i] - m_new);
                Ss[r][c0 + i] = p;
                sum += p;
            }
            sum += __shfl_xor(sum, 1);
            sum += __shfl_xor(sum, 2);
            const float alpha = __expf(m_old - m_new);
            if ((t & 3) == 0) {
                mrow[r] = m_new;
                lrow[r] = lrow[r] * alpha + sum;
                arow[r] = alpha;
            }
        }
        __syncthreads();

        // rescale + PV
        {
            float al[4];
            #pragma unroll
            for (int i = 0; i < 4; ++i) al[i] = arow[ty * 4 + i];
            #pragma unroll
            for (int i = 0; i < 4; ++i)
                #pragma unroll
                for (int j = 0; j < 4; ++j)
                    o[i][j] *= al[i];
            #pragma unroll 4
            for (int kkk = 0; kkk < 64; ++kkk) {
                float p[4], v[4];
                #pragma unroll
                for (int i = 0; i < 4; ++i) p[i] = Ss[ty * 4 + i][kkk];
                #pragma unroll
                for (int j = 0; j < 4; ++j) v[j] = Vs[kkk][tx * 4 + j];
                #pragma unroll
                for (int i = 0; i < 4; ++i)
                    #pragma unroll
                    for (int j = 0; j < 4; ++j)
                        o[i][j] += p[i] * v[j];
            }
        }
    }

    #pragma unroll
    for (int i = 0; i < 4; ++i) {
        const float invl = 1.f / lrow[ty * 4 + i];
        const int n = n0 + ty * 4 + i;
        #pragma unroll
        for (int j = 0; j < 4; ++j)
            O[(size_t)n * HID + h * HD + tx * 4 + j] = o[i][j] * invl;
    }
}

// ---------------- launch ----------------
extern "C" void kernel_launch(void* const* d_in, const int* in_sizes, int n_in,
                              void* d_out, int out_size, void* d_ws, size_t ws_size,
                              hipStream_t stream)
{
    const float* x     = (const float*)d_in[0];
    const int*   ei    = (const int*)  d_in[1];
    const float* W_in  = (const float*)d_in[2];
    const float* b_in  = (const float*)d_in[3];
    const float* plas  = (const float*)d_in[4];
    const float* syn   = (const float*)d_in[5];
    const float* inpw  = (const float*)d_in[6];
    const float* inpb  = (const float*)d_in[7];
    const float* outpw = (const float*)d_in[8];
    const float* outpb = (const float*)d_in[9];
    const float* Wout  = (const float*)d_in[10];
    const float* bout  = (const float*)d_in[11];
    float* out = (float*)d_out;

    char* ws = (char*)d_ws;
    float* h    = (float*)(ws + 0);                  //  8 MB [8192,256]
    float* h2   = (float*)(ws + (8u  << 20));        //  8 MB
    float* qkv  = (float*)(ws + (16u << 20));        // 24 MB [8192,768]
    float* aO   = (float*)(ws + (40u << 20));        //  8 MB [8192,256]
    float* tmp  = (float*)(ws + (48u << 20));        //  8 MB
    int*   rowp = (int*)  (ws + (56u << 20));        // 8193 ints
    int*   curs = (int*)  (ws + (56u << 20) + 40960);
    int*   esrc = (int*)  (ws + (56u << 20) + 81920); // E ints (2 MB)

    // CSR build (curs doubles as degree histogram)
    hipMemsetAsync(curs, 0, N_NODES * sizeof(int), stream);
    hist_kernel<<<NEDGE / 256, 256, 0, stream>>>(ei, curs);
    scan_kernel<<<1, 1024, 0, stream>>>(curs, rowp, curs);
    scatter_kernel<<<NEDGE / 256, 256, 0, stream>>>(ei, curs, esrc);

    // input projection
    gemm_bias_kernel<<<dim3(N_NODES / 64, HID / 64), 256, 0, stream>>>(
        x, W_in, b_in, h, N_NODES, HID, IND);

    // 3 GNN layers (ping-pong)
    aggregate_kernel<<<N_NODES, 256, 0, stream>>>(h,  h2, rowp, esrc, plas, syn, 0);
    aggregate_kernel<<<N_NODES, 256, 0, stream>>>(h2, h,  rowp, esrc, plas, syn, 1);
    aggregate_kernel<<<N_NODES, 256, 0, stream>>>(h,  h2, rowp, esrc, plas, syn, 2);

    // qkv projection
    gemm_bias_kernel<<<dim3(N_NODES / 64, 768 / 64), 256, 0, stream>>>(
        h2, inpw, inpb, qkv, N_NODES, 768, HID);

    // attention
    attn_kernel<<<dim3(N_NODES / 64, NHEAD), 256, 0, stream>>>(qkv, aO);

    // output projections
    gemm_bias_kernel<<<dim3(N_NODES / 64, HID / 64), 256, 0, stream>>>(
        aO, outpw, outpb, tmp, N_NODES, HID, HID);
    gemm_bias_kernel<<<dim3(N_NODES / 64, OUTD / 64), 256, 0, stream>>>(
        tmp, Wout, bout, out, N_NODES, OUTD, HID);
}

// Round 2
// 786.502 us; speedup vs baseline: 2.3215x; 2.3215x over previous
//
#include <hip/hip_runtime.h>
#include <hip/hip_bf16.h>
#include <float.h>

#define N_NODES 8192
#define NEDGE   524288
#define IND     128
#define HID     256
#define OUTD    128
#define NHEAD   4
#define HD      64

typedef short short8 __attribute__((ext_vector_type(8)));
typedef float f32x4 __attribute__((ext_vector_type(4)));

__device__ __forceinline__ float sigmoidf_(float x) { return 1.0f / (1.0f + expf(-x)); }

__device__ __forceinline__ unsigned short f2bf(float f) {
    __hip_bfloat16 b = __float2bfloat16(f);
    return __builtin_bit_cast(unsigned short, b);
}
__device__ __forceinline__ float bf2f(unsigned short u) {
    __hip_bfloat16 b = __builtin_bit_cast(__hip_bfloat16, u);
    return __bfloat162float(b);
}
__device__ __forceinline__ void split3(float x, unsigned short& a, unsigned short& b, unsigned short& c) {
    a = f2bf(x); float r = x - bf2f(a);
    b = f2bf(r); r = r - bf2f(b);
    c = f2bf(r);
}
__device__ __forceinline__ void split2(float x, unsigned short& a, unsigned short& b) {
    a = f2bf(x); float r = x - bf2f(a);
    b = f2bf(r);
}

__device__ __forceinline__ void gll16(const void* g, void* l) {
    __builtin_amdgcn_global_load_lds(
        (const __attribute__((address_space(1))) void*)g,
        (__attribute__((address_space(3))) void*)l, 16, 0, 0);
}

// ---------------- generic C[M,N] = A[M,K] * W[N,K]^T + bias ----------------
__global__ __launch_bounds__(256) void gemm_bias_kernel(
    const float* __restrict__ A, const float* __restrict__ W,
    const float* __restrict__ bias, float* __restrict__ C,
    int M, int Nn, int K)
{
    __shared__ float As[64][33];
    __shared__ float Ws[64][33];
    const int t  = threadIdx.x;
    const int tx = t & 15, ty = t >> 4;
    const int m0 = blockIdx.x * 64, n0 = blockIdx.y * 64;
    const int lr = t >> 2;
    const int lc = (t & 3) * 8;

    float acc[4][4] = {};
    for (int kk = 0; kk < K; kk += 32) {
        const float* Ap = A + (size_t)(m0 + lr) * K + kk + lc;
        const float* Wp = W + (size_t)(n0 + lr) * K + kk + lc;
        float4 a0 = *(const float4*)(Ap);
        float4 a1 = *(const float4*)(Ap + 4);
        float4 w0 = *(const float4*)(Wp);
        float4 w1 = *(const float4*)(Wp + 4);
        __syncthreads();
        As[lr][lc + 0] = a0.x; As[lr][lc + 1] = a0.y; As[lr][lc + 2] = a0.z; As[lr][lc + 3] = a0.w;
        As[lr][lc + 4] = a1.x; As[lr][lc + 5] = a1.y; As[lr][lc + 6] = a1.z; As[lr][lc + 7] = a1.w;
        Ws[lr][lc + 0] = w0.x; Ws[lr][lc + 1] = w0.y; Ws[lr][lc + 2] = w0.z; Ws[lr][lc + 3] = w0.w;
        Ws[lr][lc + 4] = w1.x; Ws[lr][lc + 5] = w1.y; Ws[lr][lc + 6] = w1.z; Ws[lr][lc + 7] = w1.w;
        __syncthreads();
        #pragma unroll 8
        for (int k = 0; k < 32; ++k) {
            float a[4], w[4];
            #pragma unroll
            for (int i = 0; i < 4; ++i) a[i] = As[ty * 4 + i][k];
            #pragma unroll
            for (int j = 0; j < 4; ++j) w[j] = Ws[tx * 4 + j][k];
            #pragma unroll
            for (int i = 0; i < 4; ++i)
                #pragma unroll
                for (int j = 0; j < 4; ++j)
                    acc[i][j] += a[i] * w[j];
        }
    }
    #pragma unroll
    for (int i = 0; i < 4; ++i) {
        const int m = m0 + ty * 4 + i;
        #pragma unroll
        for (int j = 0; j < 4; ++j) {
            const int n = n0 + tx * 4 + j;
            C[(size_t)m * Nn + n] = acc[i][j] + bias[n];
        }
    }
}

// ---------------- CSR build ----------------
__global__ void hist_kernel(const int* __restrict__ ei, int* __restrict__ deg)
{
    int e = blockIdx.x * blockDim.x + threadIdx.x;
    if (e < NEDGE) atomicAdd(&deg[ei[NEDGE + e]], 1);
}

__global__ __launch_bounds__(1024) void scan_kernel(
    const int* __restrict__ deg, int* __restrict__ row_ptr, int* __restrict__ cursor)
{
    __shared__ int sh[1024];
    const int t = threadIdx.x;
    int v[8]; int s = 0;
    #pragma unroll
    for (int i = 0; i < 8; ++i) { v[i] = deg[t * 8 + i]; s += v[i]; }
    sh[t] = s; __syncthreads();
    for (int off = 1; off < 1024; off <<= 1) {
        int add = (t >= off) ? sh[t - off] : 0;
        __syncthreads();
        sh[t] += add;
        __syncthreads();
    }
    int base = sh[t] - s;
    #pragma unroll
    for (int i = 0; i < 8; ++i) {
        row_ptr[t * 8 + i] = base;
        cursor[t * 8 + i]  = base;
        base += v[i];
    }
    if (t == 1023) row_ptr[N_NODES] = base;
}

__global__ void scatter_kernel(const int* __restrict__ ei, int* __restrict__ cursor,
                               int* __restrict__ esrc)
{
    int e = blockIdx.x * blockDim.x + threadIdx.x;
    if (e < NEDGE) {
        int d = ei[NEDGE + e];
        int p = atomicAdd(&cursor[d], 1);
        esrc[p] = ei[e];
    }
}

// ---------------- GNN aggregate ----------------
__global__ __launch_bounds__(256) void aggregate_kernel(
    const float* __restrict__ hin, float* __restrict__ hout,
    const int* __restrict__ row_ptr, const int* __restrict__ esrc,
    const float* __restrict__ plas, const float* __restrict__ syn, int layer)
{
    const int b = blockIdx.x;
    const int c = threadIdx.x;
    const int st = row_ptr[b], en = row_ptr[b + 1];
    float a0 = 0.f, a1 = 0.f, a2 = 0.f, a3 = 0.f;
    int e = st;
    for (; e + 4 <= en; e += 4) {
        int s0 = esrc[e], s1 = esrc[e + 1], s2 = esrc[e + 2], s3 = esrc[e + 3];
        a0 += hin[(size_t)s0 * HID + c];
        a1 += hin[(size_t)s1 * HID + c];
        a2 += hin[(size_t)s2 * HID + c];
        a3 += hin[(size_t)s3 * HID + c];
    }
    float acc = (a0 + a1) + (a2 + a3);
    for (; e < en; ++e) acc += hin[(size_t)esrc[e] * HID + c];
    const float scale = sigmoidf_(plas[layer]) * sigmoidf_(syn[layer]);
    float x = acc * scale;
    hout[(size_t)b * HID + c] = (x > 0.f) ? x : 0.01f * x;
}

// ---------------- pre-pass: split K (3 bf16 comps, chunk-swizzled) and V (2 comps, transposed+swizzled)
// Kc layout: [head][n][64] bf16, 16B-chunk j stored at j^(n&7).
// Vt layout: [head][64 d][8192 n] bf16, within each 64-n group chunk nc stored at nc^(d&7).
__global__ __launch_bounds__(256) void split_kernel(
    const float* __restrict__ qkv,
    unsigned short* __restrict__ Kc0, unsigned short* __restrict__ Kc1,
    unsigned short* __restrict__ Kc2,
    unsigned short* __restrict__ Vt0, unsigned short* __restrict__ Vt1)
{
    __shared__ unsigned short vts[2][64 * 72];
    const int h  = blockIdx.y;
    const int n0 = blockIdx.x * 64;
    const int t  = threadIdx.x;
    const int r  = t >> 2;          // node row 0..63
    const int n  = n0 + r;
    const int dc = (t & 3) * 16;    // d-col start

    // K split
    {
        const float* kp = qkv + (size_t)n * 768 + 256 + h * 64 + dc;
        float kv[16];
        #pragma unroll
        for (int i = 0; i < 16; i += 4) {
            float4 f = *(const float4*)(kp + i);
            kv[i] = f.x; kv[i+1] = f.y; kv[i+2] = f.z; kv[i+3] = f.w;
        }
        #pragma unroll
        for (int half = 0; half < 2; ++half) {
            short8 c0, c1, c2;
            #pragma unroll
            for (int j = 0; j < 8; ++j) {
                unsigned short a, b, c;
                split3(kv[half * 8 + j], a, b, c);
                c0[j] = (short)a; c1[j] = (short)b; c2[j] = (short)c;
            }
            const int pos = ((dc >> 3) + half) ^ (n & 7);
            const size_t base = ((size_t)(h * 8192 + n)) * 64 + pos * 8;
            *(short8*)(Kc0 + base) = c0;
            *(short8*)(Kc1 + base) = c1;
            *(short8*)(Kc2 + base) = c2;
        }
    }
    // V split into LDS (transpose)
    {
        const float* vp = qkv + (size_t)n * 768 + 512 + h * 64 + dc;
        #pragma unroll
        for (int i = 0; i < 16; i += 4) {
            float4 f = *(const float4*)(vp + i);
            float vv[4] = {f.x, f.y, f.z, f.w};
            #pragma unroll
            for (int k2 = 0; k2 < 4; ++k2) {
                unsigned short a, b;
                split2(vv[k2], a, b);
                const int d = dc + i + k2;
                vts[0][d * 72 + r] = a;
                vts[1][d * 72 + r] = b;
            }
        }
    }
    __syncthreads();
    // write Vt rows (coalesced 16B chunks, swizzled)
    #pragma unroll
    for (int i = 0; i < 4; ++i) {
        const int q = t * 4 + i;
        const int c = q >> 9, d = (q >> 3) & 63, nc = q & 7;
        short8 vv = *(const short8*)(&vts[c][d * 72 + nc * 8]);
        unsigned short* dstp = (c == 0) ? Vt0 : Vt1;
        const size_t dst = ((size_t)(h * 64 + d)) * 8192 + n0 + ((nc ^ (d & 7)) * 8);
        *(short8*)(dstp + dst) = vv;
    }
}

// ---------------- MFMA flash attention, split-precision bf16 ----------------
// 4 waves/block, 16 q-rows/wave, 64-key tiles. LDS: K 3comps + V 2comps (40KB) + P per-wave (16KB).
__global__ __launch_bounds__(256) void attn_mfma_kernel(
    const float* __restrict__ qkv,
    const unsigned short* __restrict__ Kc0, const unsigned short* __restrict__ Kc1,
    const unsigned short* __restrict__ Kc2,
    const unsigned short* __restrict__ Vt0, const unsigned short* __restrict__ Vt1,
    float* __restrict__ aO)
{
    __shared__ __align__(16) char smem[57344];
    const int h    = blockIdx.y;
    const int n0   = blockIdx.x * 64;
    const int t    = threadIdx.x;
    const int w    = t >> 6;
    const int lane = t & 63;
    const int l15  = lane & 15, l4 = lane >> 4;
    const int qbase = n0 + w * 16;

    // ---- Q load + 3-way split (pre-scaled by 1/sqrt(HD)=0.125)
    short8 qf[3][2];
    #pragma unroll
    for (int ks = 0; ks < 2; ++ks) {
        const float* qp = qkv + (size_t)(qbase + l15) * 768 + h * 64 + ks * 32 + l4 * 8;
        float4 qa = *(const float4*)qp, qb = *(const float4*)(qp + 4);
        float qv[8] = {qa.x, qa.y, qa.z, qa.w, qb.x, qb.y, qb.z, qb.w};
        #pragma unroll
        for (int j = 0; j < 8; ++j) {
            unsigned short a, b, c;
            split3(qv[j] * 0.125f, a, b, c);
            qf[0][ks][j] = (short)a; qf[1][ks][j] = (short)b; qf[2][ks][j] = (short)c;
        }
    }

    // ---- staging descriptors: 40 x 1KB segments, 10 per wave
    // seg -> comp c = seg>>3 (0..2: Kc, 3..4: Vt), rowblk = seg&7
    const char* sgb[10];
    int sgstride[10];
    int sgl[10];
    #pragma unroll
    for (int s = 0; s < 10; ++s) {
        const int seg = w * 10 + s;
        const int c = seg >> 3, rb = seg & 7;
        const int rloc = rb * 8 + (lane >> 3), cloc = lane & 7;
        if (c < 3) {
            const unsigned short* base = (c == 0) ? Kc0 : ((c == 1) ? Kc1 : Kc2);
            sgb[s] = (const char*)(base + ((size_t)(h * 8192 + rloc)) * 64 + cloc * 8);
            sgstride[s] = 64 * 64 * 2;   // 64 rows x 128B per k-tile
        } else {
            const unsigned short* base = (c == 3) ? Vt0 : Vt1;
            sgb[s] = (const char*)(base + ((size_t)(h * 64 + rloc)) * 8192 + cloc * 8);
            sgstride[s] = 64 * 2;        // 64 cols x 2B per k-tile
        }
        sgl[s] = seg * 1024;
    }

    auto STAGE = [&](int kt) {
        #pragma unroll
        for (int s = 0; s < 10; ++s) {
            gll16(sgb[s] + (size_t)kt * sgstride[s], &smem[sgl[s]]);
        }
    };

    f32x4 o[4];
    float mrow[4], lsum[4];
    #pragma unroll
    for (int r = 0; r < 4; ++r) {
        o[r] = (f32x4){0.f, 0.f, 0.f, 0.f};
        mrow[r] = -FLT_MAX; lsum[r] = 0.f;
    }

    const int psoff = 40960 + w * 4096;

    STAGE(0);
    __syncthreads();

    for (int kt = 0; kt < N_NODES / 64; ++kt) {
        // ---- QK^T: 6-term split-precision (error ~fp32 level)
        f32x4 sacc[4];
        #pragma unroll
        for (int nt = 0; nt < 4; ++nt) {
            f32x4 s = (f32x4){0.f, 0.f, 0.f, 0.f};
            const int row = nt * 16 + l15;
            #pragma unroll
            for (int ks = 0; ks < 2; ++ks) {
                const int rb = row * 128 + (((ks * 4 + l4) ^ (row & 7)) * 16);
                short8 kb0 = *(const short8*)(&smem[rb]);
                short8 kb1 = *(const short8*)(&smem[8192 + rb]);
                short8 kb2 = *(const short8*)(&smem[16384 + rb]);
                s = __builtin_amdgcn_mfma_f32_16x16x32_bf16(qf[2][ks], kb0, s, 0, 0, 0);
                s = __builtin_amdgcn_mfma_f32_16x16x32_bf16(qf[1][ks], kb1, s, 0, 0, 0);
                s = __builtin_amdgcn_mfma_f32_16x16x32_bf16(qf[0][ks], kb2, s, 0, 0, 0);
                s = __builtin_amdgcn_mfma_f32_16x16x32_bf16(qf[1][ks], kb0, s, 0, 0, 0);
                s = __builtin_amdgcn_mfma_f32_16x16x32_bf16(qf[0][ks], kb1, s, 0, 0, 0);
                s = __builtin_amdgcn_mfma_f32_16x16x32_bf16(qf[0][ks], kb0, s, 0, 0, 0);
            }
            sacc[nt] = s;
        }
        // ---- online softmax (lane-local rows: row = l4*4+r, col = nt*16+l15)
        float alr[4];
        #pragma unroll
        for (int r = 0; r < 4; ++r) {
            float mx = fmaxf(fmaxf(sacc[0][r], sacc[1][r]), fmaxf(sacc[2][r], sacc[3][r]));
            mx = fmaxf(mx, __shfl_xor(mx, 1));
            mx = fmaxf(mx, __shfl_xor(mx, 2));
            mx = fmaxf(mx, __shfl_xor(mx, 4));
            mx = fmaxf(mx, __shfl_xor(mx, 8));
            const float mn = fmaxf(mrow[r], mx);
            const float al = __expf(mrow[r] - mn);
            mrow[r] = mn;
            float ps = 0.f;
            #pragma unroll
            for (int nt = 0; nt < 4; ++nt) {
                float p = __expf(sacc[nt][r] - mn);
                sacc[nt][r] = p;
                ps += p;
            }
            ps += __shfl_xor(ps, 1);
            ps += __shfl_xor(ps, 2);
            ps += __shfl_xor(ps, 4);
            ps += __shfl_xor(ps, 8);
            lsum[r] = lsum[r] * al + ps;
            alr[r] = al;
        }
        #pragma unroll
        for (int dt = 0; dt < 4; ++dt)
            #pragma unroll
            for (int r = 0; r < 4; ++r)
                o[dt][r] *= alr[r];
        // ---- P -> per-wave LDS (f32, chunk-swizzled by row&7)
        #pragma unroll
        for (int nt = 0; nt < 4; ++nt) {
            #pragma unroll
            for (int r = 0; r < 4; ++r) {
                const int prow = l4 * 4 + r;
                const int col = nt * 16 + l15;
                const int ch = (col >> 2) ^ (prow & 7);
                *(float*)(&smem[psoff + prow * 256 + ch * 16 + (col & 3) * 4]) = sacc[nt][r];
            }
        }
        // ---- PV: P 2-split x V 2-split, 3 terms
        #pragma unroll
        for (int ks = 0; ks < 2; ++ks) {
            const int chb = ks * 8 + l4 * 2;
            f32x4 pA = *(const f32x4*)(&smem[psoff + l15 * 256 + (((chb + 0) ^ (l15 & 7)) * 16)]);
            f32x4 pB = *(const f32x4*)(&smem[psoff + l15 * 256 + (((chb + 1) ^ (l15 & 7)) * 16)]);
            float pv8[8] = {pA[0], pA[1], pA[2], pA[3], pB[0], pB[1], pB[2], pB[3]};
            short8 pa0, pa1;
            #pragma unroll
            for (int j = 0; j < 8; ++j) {
                unsigned short a, b;
                split2(pv8[j], a, b);
                pa0[j] = (short)a; pa1[j] = (short)b;
            }
            #pragma unroll
            for (int dt = 0; dt < 4; ++dt) {
                const int vrow = dt * 16 + l15;
                const int vb = vrow * 128 + (((ks * 4 + l4) ^ (vrow & 7)) * 16);
                short8 v0 = *(const short8*)(&smem[24576 + vb]);
                short8 v1 = *(const short8*)(&smem[32768 + vb]);
                o[dt] = __builtin_amdgcn_mfma_f32_16x16x32_bf16(pa1, v0, o[dt], 0, 0, 0);
                o[dt] = __builtin_amdgcn_mfma_f32_16x16x32_bf16(pa0, v1, o[dt], 0, 0, 0);
                o[dt] = __builtin_amdgcn_mfma_f32_16x16x32_bf16(pa0, v0, o[dt], 0, 0, 0);
            }
        }
        __syncthreads();                 // all waves done reading K/V tile
        if (kt < N_NODES / 64 - 1) STAGE(kt + 1);
        __syncthreads();                 // staged data visible
    }

    // ---- epilogue
    #pragma unroll
    for (int r = 0; r < 4; ++r) {
        const float inv = 1.f / lsum[r];
        const int n = qbase + l4 * 4 + r;
        #pragma unroll
        for (int dt = 0; dt < 4; ++dt)
            aO[(size_t)n * 256 + h * 64 + dt * 16 + l15] = o[dt][r] * inv;
    }
}

// ---------------- launch ----------------
extern "C" void kernel_launch(void* const* d_in, const int* in_sizes, int n_in,
                              void* d_out, int out_size, void* d_ws, size_t ws_size,
                              hipStream_t stream)
{
    const float* x     = (const float*)d_in[0];
    const int*   ei    = (const int*)  d_in[1];
    const float* W_in  = (const float*)d_in[2];
    const float* b_in  = (const float*)d_in[3];
    const float* plas  = (const float*)d_in[4];
    const float* syn   = (const float*)d_in[5];
    const float* inpw  = (const float*)d_in[6];
    const float* inpb  = (const float*)d_in[7];
    const float* outpw = (const float*)d_in[8];
    const float* outpb = (const float*)d_in[9];
    const float* Wout  = (const float*)d_in[10];
    const float* bout  = (const float*)d_in[11];
    float* out = (float*)d_out;

    char* ws = (char*)d_ws;
    // time-shared layout (58.1 MiB total, same footprint as round 1):
    //  0..8MB   : h   (GNN phase)      -> Kc0(0..4), Kc1(4..8)   (attn phase)
    //  8..16MB  : h2  (GNN phase)      -> Kc2(8..12), Vt0(12..16)
    // 16..40MB  : qkv (live through attn: Q is read from it)
    // 40..48MB  : aO
    // 48..56MB  : Vt1 (attn phase)     -> tmp (post-attn gemm)
    // 56MB..    : rowp, curs, esrc
    float* h    = (float*)(ws + 0);
    float* h2   = (float*)(ws + (8u  << 20));
    float* qkv  = (float*)(ws + (16u << 20));
    float* aO   = (float*)(ws + (40u << 20));
    float* tmp  = (float*)(ws + (48u << 20));
    unsigned short* Kc0 = (unsigned short*)(ws + 0);
    unsigned short* Kc1 = (unsigned short*)(ws + (4u  << 20));
    unsigned short* Kc2 = (unsigned short*)(ws + (8u  << 20));
    unsigned short* Vt0 = (unsigned short*)(ws + (12u << 20));
    unsigned short* Vt1 = (unsigned short*)(ws + (48u << 20));
    int* rowp = (int*)(ws + (56u << 20));
    int* curs = (int*)(ws + (56u << 20) + 40960);
    int* esrc = (int*)(ws + (56u << 20) + 81920);

    // CSR build
    hipMemsetAsync(curs, 0, N_NODES * sizeof(int), stream);
    hist_kernel<<<NEDGE / 256, 256, 0, stream>>>(ei, curs);
    scan_kernel<<<1, 1024, 0, stream>>>(curs, rowp, curs);
    scatter_kernel<<<NEDGE / 256, 256, 0, stream>>>(ei, curs, esrc);

    // input projection
    gemm_bias_kernel<<<dim3(N_NODES / 64, HID / 64), 256, 0, stream>>>(
        x, W_in, b_in, h, N_NODES, HID, IND);

    // 3 GNN layers
    aggregate_kernel<<<N_NODES, 256, 0, stream>>>(h,  h2, rowp, esrc, plas, syn, 0);
    aggregate_kernel<<<N_NODES, 256, 0, stream>>>(h2, h,  rowp, esrc, plas, syn, 1);
    aggregate_kernel<<<N_NODES, 256, 0, stream>>>(h,  h2, rowp, esrc, plas, syn, 2);

    // qkv projection
    gemm_bias_kernel<<<dim3(N_NODES / 64, 768 / 64), 256, 0, stream>>>(
        h2, inpw, inpb, qkv, N_NODES, 768, HID);

    // split pre-pass (K 3-comp swizzled, V 2-comp transposed+swizzled)
    split_kernel<<<dim3(N_NODES / 64, NHEAD), 256, 0, stream>>>(
        qkv, Kc0, Kc1, Kc2, Vt0, Vt1);

    // MFMA attention
    attn_mfma_kernel<<<dim3(N_NODES / 64, NHEAD), 256, 0, stream>>>(
        qkv, Kc0, Kc1, Kc2, Vt0, Vt1, aO);

    // output projections
    gemm_bias_kernel<<<dim3(N_NODES / 64, HID / 64), 256, 0, stream>>>(
        aO, outpw, outpb, tmp, N_NODES, HID, HID);
    gemm_bias_kernel<<<dim3(N_NODES / 64, OUTD / 64), 256, 0, stream>>>(
        tmp, Wout, bout, out, N_NODES, OUTD, HID);
}

// Round 3
// 691.517 us; speedup vs baseline: 2.6404x; 1.1374x over previous
//
#include <hip/hip_runtime.h>
#include <hip/hip_bf16.h>
#include <float.h>

#define N_NODES 8192
#define NEDGE   524288
#define IND     128
#define HID     256
#define OUTD    128
#define NHEAD   4
#define HD      64

typedef short short8 __attribute__((ext_vector_type(8)));
typedef float f32x4 __attribute__((ext_vector_type(4)));

__device__ __forceinline__ float sigmoidf_(float x) { return 1.0f / (1.0f + expf(-x)); }

__device__ __forceinline__ unsigned short f2bf(float f) {
    __hip_bfloat16 b = __float2bfloat16(f);
    return __builtin_bit_cast(unsigned short, b);
}
__device__ __forceinline__ float bf2f(unsigned short u) {
    __hip_bfloat16 b = __builtin_bit_cast(__hip_bfloat16, u);
    return __bfloat162float(b);
}
__device__ __forceinline__ void split3(float x, unsigned short& a, unsigned short& b, unsigned short& c) {
    a = f2bf(x); float r = x - bf2f(a);
    b = f2bf(r); r = r - bf2f(b);
    c = f2bf(r);
}
__device__ __forceinline__ unsigned int pack2(float lo, float hi) {
    return (unsigned int)f2bf(lo) | ((unsigned int)f2bf(hi) << 16);
}

__device__ __forceinline__ void gll16(const void* g, void* l) {
    __builtin_amdgcn_global_load_lds(
        (const __attribute__((address_space(1))) void*)g,
        (__attribute__((address_space(3))) void*)l, 16, 0, 0);
}

// ---------------- generic C[M,N] = A[M,K] * W[N,K]^T + bias ----------------
__global__ __launch_bounds__(256) void gemm_bias_kernel(
    const float* __restrict__ A, const float* __restrict__ W,
    const float* __restrict__ bias, float* __restrict__ C,
    int M, int Nn, int K)
{
    __shared__ float As[64][33];
    __shared__ float Ws[64][33];
    const int t  = threadIdx.x;
    const int tx = t & 15, ty = t >> 4;
    const int m0 = blockIdx.x * 64, n0 = blockIdx.y * 64;
    const int lr = t >> 2;
    const int lc = (t & 3) * 8;

    float acc[4][4] = {};
    for (int kk = 0; kk < K; kk += 32) {
        const float* Ap = A + (size_t)(m0 + lr) * K + kk + lc;
        const float* Wp = W + (size_t)(n0 + lr) * K + kk + lc;
        float4 a0 = *(const float4*)(Ap);
        float4 a1 = *(const float4*)(Ap + 4);
        float4 w0 = *(const float4*)(Wp);
        float4 w1 = *(const float4*)(Wp + 4);
        __syncthreads();
        As[lr][lc + 0] = a0.x; As[lr][lc + 1] = a0.y; As[lr][lc + 2] = a0.z; As[lr][lc + 3] = a0.w;
        As[lr][lc + 4] = a1.x; As[lr][lc + 5] = a1.y; As[lr][lc + 6] = a1.z; As[lr][lc + 7] = a1.w;
        Ws[lr][lc + 0] = w0.x; Ws[lr][lc + 1] = w0.y; Ws[lr][lc + 2] = w0.z; Ws[lr][lc + 3] = w0.w;
        Ws[lr][lc + 4] = w1.x; Ws[lr][lc + 5] = w1.y; Ws[lr][lc + 6] = w1.z; Ws[lr][lc + 7] = w1.w;
        __syncthreads();
        #pragma unroll 8
        for (int k = 0; k < 32; ++k) {
            float a[4], w[4];
            #pragma unroll
            for (int i = 0; i < 4; ++i) a[i] = As[ty * 4 + i][k];
            #pragma unroll
            for (int j = 0; j < 4; ++j) w[j] = Ws[tx * 4 + j][k];
            #pragma unroll
            for (int i = 0; i < 4; ++i)
                #pragma unroll
                for (int j = 0; j < 4; ++j)
                    acc[i][j] += a[i] * w[j];
        }
    }
    #pragma unroll
    for (int i = 0; i < 4; ++i) {
        const int m = m0 + ty * 4 + i;
        #pragma unroll
        for (int j = 0; j < 4; ++j) {
            const int n = n0 + tx * 4 + j;
            C[(size_t)m * Nn + n] = acc[i][j] + bias[n];
        }
    }
}

// ---------------- CSR build ----------------
__global__ void hist_kernel(const int* __restrict__ ei, int* __restrict__ deg)
{
    int e = blockIdx.x * blockDim.x + threadIdx.x;
    if (e < NEDGE) atomicAdd(&deg[ei[NEDGE + e]], 1);
}

__global__ __launch_bounds__(1024) void scan_kernel(
    const int* __restrict__ deg, int* __restrict__ row_ptr, int* __restrict__ cursor)
{
    __shared__ int sh[1024];
    const int t = threadIdx.x;
    int v[8]; int s = 0;
    #pragma unroll
    for (int i = 0; i < 8; ++i) { v[i] = deg[t * 8 + i]; s += v[i]; }
    sh[t] = s; __syncthreads();
    for (int off = 1; off < 1024; off <<= 1) {
        int add = (t >= off) ? sh[t - off] : 0;
        __syncthreads();
        sh[t] += add;
        __syncthreads();
    }
    int base = sh[t] - s;
    #pragma unroll
    for (int i = 0; i < 8; ++i) {
        row_ptr[t * 8 + i] = base;
        cursor[t * 8 + i]  = base;
        base += v[i];
    }
    if (t == 1023) row_ptr[N_NODES] = base;
}

__global__ void scatter_kernel(const int* __restrict__ ei, int* __restrict__ cursor,
                               int* __restrict__ esrc)
{
    int e = blockIdx.x * blockDim.x + threadIdx.x;
    if (e < NEDGE) {
        int d = ei[NEDGE + e];
        int p = atomicAdd(&cursor[d], 1);
        esrc[p] = ei[e];
    }
}

// ---------------- GNN aggregate ----------------
__global__ __launch_bounds__(256) void aggregate_kernel(
    const float* __restrict__ hin, float* __restrict__ hout,
    const int* __restrict__ row_ptr, const int* __restrict__ esrc,
    const float* __restrict__ plas, const float* __restrict__ syn, int layer)
{
    const int b = blockIdx.x;
    const int c = threadIdx.x;
    const int st = row_ptr[b], en = row_ptr[b + 1];
    float a0 = 0.f, a1 = 0.f, a2 = 0.f, a3 = 0.f;
    int e = st;
    for (; e + 4 <= en; e += 4) {
        int s0 = esrc[e], s1 = esrc[e + 1], s2 = esrc[e + 2], s3 = esrc[e + 3];
        a0 += hin[(size_t)s0 * HID + c];
        a1 += hin[(size_t)s1 * HID + c];
        a2 += hin[(size_t)s2 * HID + c];
        a3 += hin[(size_t)s3 * HID + c];
    }
    float acc = (a0 + a1) + (a2 + a3);
    for (; e < en; ++e) acc += hin[(size_t)esrc[e] * HID + c];
    const float scale = sigmoidf_(plas[layer]) * sigmoidf_(syn[layer]);
    float x = acc * scale;
    hout[(size_t)b * HID + c] = (x > 0.f) ? x : 0.01f * x;
}

// ---------------- pre-pass: split K (3 bf16 comps, chunk-swizzled), V (1 comp, transposed+swizzled)
// Kc layout: [head][n][64] bf16, 16B-chunk j stored at j^(n&7).
// Vt layout: [head][64 d][8192 n] bf16, within each 64-n group chunk nc stored at nc^(d&7).
__global__ __launch_bounds__(256) void split_kernel(
    const float* __restrict__ qkv,
    unsigned short* __restrict__ Kc0, unsigned short* __restrict__ Kc1,
    unsigned short* __restrict__ Kc2, unsigned short* __restrict__ Vt0)
{
    __shared__ unsigned short vts[64 * 80];
    const int h  = blockIdx.y;
    const int n0 = blockIdx.x * 64;
    const int t  = threadIdx.x;
    const int r  = t >> 2;          // node row 0..63
    const int n  = n0 + r;
    const int dc = (t & 3) * 16;    // d-col start

    // K split (3 comps)
    {
        const float* kp = qkv + (size_t)n * 768 + 256 + h * 64 + dc;
        float kv[16];
        #pragma unroll
        for (int i = 0; i < 16; i += 4) {
            float4 f = *(const float4*)(kp + i);
            kv[i] = f.x; kv[i+1] = f.y; kv[i+2] = f.z; kv[i+3] = f.w;
        }
        #pragma unroll
        for (int half = 0; half < 2; ++half) {
            short8 c0, c1, c2;
            #pragma unroll
            for (int j = 0; j < 8; ++j) {
                unsigned short a, b, c;
                split3(kv[half * 8 + j], a, b, c);
                c0[j] = (short)a; c1[j] = (short)b; c2[j] = (short)c;
            }
            const int pos = ((dc >> 3) + half) ^ (n & 7);
            const size_t base = ((size_t)(h * 8192 + n)) * 64 + pos * 8;
            *(short8*)(Kc0 + base) = c0;
            *(short8*)(Kc1 + base) = c1;
            *(short8*)(Kc2 + base) = c2;
        }
    }
    // V -> bf16, transpose via LDS
    {
        const float* vp = qkv + (size_t)n * 768 + 512 + h * 64 + dc;
        #pragma unroll
        for (int i = 0; i < 16; i += 4) {
            float4 f = *(const float4*)(vp + i);
            float vv[4] = {f.x, f.y, f.z, f.w};
            #pragma unroll
            for (int k2 = 0; k2 < 4; ++k2)
                vts[(dc + i + k2) * 80 + r] = f2bf(vv[k2]);
        }
    }
    __syncthreads();
    // write Vt rows (coalesced 16B chunks, swizzled by d&7)
    #pragma unroll
    for (int i = 0; i < 2; ++i) {
        const int q = t * 2 + i;            // 0..511: d(64) x nc(8)
        const int d = q >> 3, nc = q & 7;
        short8 vv = *(const short8*)(&vts[d * 80 + nc * 8]);
        const size_t dst = ((size_t)(h * 64 + d)) * 8192 + n0 + ((nc ^ (d & 7)) * 8);
        *(short8*)(Vt0 + dst) = vv;
    }
}

// ---------------- MFMA flash attention (swapped-operand), split-precision QK ----------------
// 4 waves/block, 32 q-rows/wave (2 q-sets of 16), 128 q/block, 64-key tiles.
// LDS: K 3 comps (24KB) + V 1 comp (8KB) + per-wave P buffers (16KB) = 48KB.
__global__ __launch_bounds__(256) void attn_mfma_kernel(
    const float* __restrict__ qkv,
    const unsigned short* __restrict__ Kc0, const unsigned short* __restrict__ Kc1,
    const unsigned short* __restrict__ Kc2, const unsigned short* __restrict__ Vt0,
    float* __restrict__ aO)
{
    __shared__ __align__(16) char smem[49152];
    const int h    = blockIdx.y;
    const int n0   = blockIdx.x * 128;
    const int t    = threadIdx.x;
    const int wv   = t >> 6;
    const int lane = t & 63;
    const int l15  = lane & 15, l4 = lane >> 4;
    const int qbase = n0 + wv * 32;

    // ---- Q load + 3-way split (pre-scaled by 1/sqrt(HD)=0.125); B-frag per-lane data
    short8 qf[2][3][2];
    #pragma unroll
    for (int qs = 0; qs < 2; ++qs) {
        #pragma unroll
        for (int ks = 0; ks < 2; ++ks) {
            const float* qp = qkv + (size_t)(qbase + qs * 16 + l15) * 768 + h * 64 + ks * 32 + l4 * 8;
            float4 qa = *(const float4*)qp, qb = *(const float4*)(qp + 4);
            float qv[8] = {qa.x, qa.y, qa.z, qa.w, qb.x, qb.y, qb.z, qb.w};
            #pragma unroll
            for (int j = 0; j < 8; ++j) {
                unsigned short a, b, c;
                split3(qv[j] * 0.125f, a, b, c);
                qf[qs][0][ks][j] = (short)a;
                qf[qs][1][ks][j] = (short)b;
                qf[qs][2][ks][j] = (short)c;
            }
        }
    }

    // ---- staging: 32 x 1KB segments; wave wv stages component wv (Kc0..2, Vt0)
    const unsigned short* cbase = (wv == 0) ? Kc0 : (wv == 1) ? Kc1 : (wv == 2) ? Kc2 : Vt0;
    const char* sgb[8];
    #pragma unroll
    for (int s = 0; s < 8; ++s) {
        const int row = s * 8 + (lane >> 3);
        if (wv < 3)
            sgb[s] = (const char*)(cbase + ((size_t)(h * 8192 + row)) * 64 + (lane & 7) * 8);
        else
            sgb[s] = (const char*)(cbase + ((size_t)(h * 64 + row)) * 8192 + (lane & 7) * 8);
    }
    const int ktstride = (wv < 3) ? 8192 : 128;   // bytes per k-tile step

    auto STAGE = [&](int kt) {
        #pragma unroll
        for (int s = 0; s < 8; ++s)
            gll16(sgb[s] + (size_t)kt * ktstride, &smem[wv * 8192 + s * 1024]);
    };

    f32x4 o[2][4];
    float mrow[2], lsum[2];
    #pragma unroll
    for (int qs = 0; qs < 2; ++qs) {
        mrow[qs] = -FLT_MAX; lsum[qs] = 0.f;
        #pragma unroll
        for (int dt = 0; dt < 4; ++dt) o[qs][dt] = (f32x4){0.f, 0.f, 0.f, 0.f};
    }

    const int pbase = 32768 + wv * 4096;

    STAGE(0);
    __syncthreads();

    for (int kt = 0; kt < N_NODES / 64; ++kt) {
        // ---- QK^T (swapped: S^T[key][q]), 6-term split-precision
        f32x4 sacc[2][4];
        #pragma unroll
        for (int qs = 0; qs < 2; ++qs)
            #pragma unroll
            for (int nt = 0; nt < 4; ++nt) sacc[qs][nt] = (f32x4){0.f, 0.f, 0.f, 0.f};

        #pragma unroll
        for (int ntk = 0; ntk < 4; ++ntk) {
            const int key = ntk * 16 + l15;
            const int rowb = key * 128;
            #pragma unroll
            for (int ks = 0; ks < 2; ++ks) {
                const int cb = (((ks * 4 + l4) ^ (key & 7)) * 16);
                short8 kb0 = *(const short8*)(&smem[rowb + cb]);
                short8 kb1 = *(const short8*)(&smem[8192 + rowb + cb]);
                short8 kb2 = *(const short8*)(&smem[16384 + rowb + cb]);
                #pragma unroll
                for (int qs = 0; qs < 2; ++qs) {
                    f32x4 s = sacc[qs][ntk];
                    s = __builtin_amdgcn_mfma_f32_16x16x32_bf16(kb0, qf[qs][2][ks], s, 0, 0, 0);
                    s = __builtin_amdgcn_mfma_f32_16x16x32_bf16(kb1, qf[qs][1][ks], s, 0, 0, 0);
                    s = __builtin_amdgcn_mfma_f32_16x16x32_bf16(kb2, qf[qs][0][ks], s, 0, 0, 0);
                    s = __builtin_amdgcn_mfma_f32_16x16x32_bf16(kb0, qf[qs][1][ks], s, 0, 0, 0);
                    s = __builtin_amdgcn_mfma_f32_16x16x32_bf16(kb1, qf[qs][0][ks], s, 0, 0, 0);
                    s = __builtin_amdgcn_mfma_f32_16x16x32_bf16(kb0, qf[qs][0][ks], s, 0, 0, 0);
                    sacc[qs][ntk] = s;
                }
            }
        }

        // ---- online softmax (per lane: q = l15, 16 keys; reduce across l4 via xor 16/32)
        #pragma unroll
        for (int qs = 0; qs < 2; ++qs) {
            float mx = -FLT_MAX;
            #pragma unroll
            for (int nt = 0; nt < 4; ++nt)
                #pragma unroll
                for (int r = 0; r < 4; ++r) mx = fmaxf(mx, sacc[qs][nt][r]);
            mx = fmaxf(mx, __shfl_xor(mx, 16));
            mx = fmaxf(mx, __shfl_xor(mx, 32));
            const float mn = fmaxf(mrow[qs], mx);
            const float alpha = __expf(mrow[qs] - mn);
            mrow[qs] = mn;
            float ps = 0.f;
            #pragma unroll
            for (int nt = 0; nt < 4; ++nt)
                #pragma unroll
                for (int r = 0; r < 4; ++r) {
                    float p = __expf(sacc[qs][nt][r] - mn);
                    sacc[qs][nt][r] = p;
                    ps += p;
                }
            ps += __shfl_xor(ps, 16);
            ps += __shfl_xor(ps, 32);
            lsum[qs] = lsum[qs] * alpha + ps;
            #pragma unroll
            for (int dt = 0; dt < 4; ++dt) o[qs][dt] *= alpha;

            // pack P to bf16 pairs, scatter into per-wave P buffer in B-frag order
            #pragma unroll
            for (int nt = 0; nt < 4; ++nt) {
                #pragma unroll
                for (int w2 = 0; w2 < 2; ++w2) {
                    unsigned int pw = pack2(sacc[qs][nt][2 * w2], sacc[qs][nt][2 * w2 + 1]);
                    const int ks_ = nt >> 1;
                    const int l4t = (nt & 1) * 2 + (l4 >> 1);
                    const int jd  = (l4 & 1) * 2 + w2;
                    *(unsigned int*)(&smem[pbase + qs * 2048 + ks_ * 1024 + l4t * 256 + l15 * 16 + jd * 4]) = pw;
                }
            }
        }

        // ---- PV: O^T[d][q] += V^T[d][k] P^T[k][q] (single bf16 term)
        #pragma unroll
        for (int ks = 0; ks < 2; ++ks) {
            short8 pb0 = *(const short8*)(&smem[pbase + 0 * 2048 + ks * 1024 + lane * 16]);
            short8 pb1 = *(const short8*)(&smem[pbase + 1 * 2048 + ks * 1024 + lane * 16]);
            #pragma unroll
            for (int dt = 0; dt < 4; ++dt) {
                const int d = dt * 16 + l15;
                short8 va = *(const short8*)(&smem[24576 + d * 128 + (((ks * 4 + l4) ^ (d & 7)) * 16)]);
                o[0][dt] = __builtin_amdgcn_mfma_f32_16x16x32_bf16(va, pb0, o[0][dt], 0, 0, 0);
                o[1][dt] = __builtin_amdgcn_mfma_f32_16x16x32_bf16(va, pb1, o[1][dt], 0, 0, 0);
            }
        }

        __syncthreads();                 // all waves done reading K/V tile
        if (kt < N_NODES / 64 - 1) STAGE(kt + 1);
        __syncthreads();                 // staged data visible
    }

    // ---- epilogue: O^T -> aO rows; d = dt*16 + l4*4 + r, q = qs*16 + l15
    #pragma unroll
    for (int qs = 0; qs < 2; ++qs) {
        const float inv = 1.f / lsum[qs];
        const int n = qbase + qs * 16 + l15;
        #pragma unroll
        for (int dt = 0; dt < 4; ++dt) {
            f32x4 ov = o[qs][dt];
            float4 st = {ov[0] * inv, ov[1] * inv, ov[2] * inv, ov[3] * inv};
            *(float4*)(&aO[(size_t)n * 256 + h * 64 + dt * 16 + l4 * 4]) = st;
        }
    }
}

// ---------------- launch ----------------
extern "C" void kernel_launch(void* const* d_in, const int* in_sizes, int n_in,
                              void* d_out, int out_size, void* d_ws, size_t ws_size,
                              hipStream_t stream)
{
    const float* x     = (const float*)d_in[0];
    const int*   ei    = (const int*)  d_in[1];
    const float* W_in  = (const float*)d_in[2];
    const float* b_in  = (const float*)d_in[3];
    const float* plas  = (const float*)d_in[4];
    const float* syn   = (const float*)d_in[5];
    const float* inpw  = (const float*)d_in[6];
    const float* inpb  = (const float*)d_in[7];
    const float* outpw = (const float*)d_in[8];
    const float* outpb = (const float*)d_in[9];
    const float* Wout  = (const float*)d_in[10];
    const float* bout  = (const float*)d_in[11];
    float* out = (float*)d_out;

    char* ws = (char*)d_ws;
    // layout (same 58.1 MiB footprint as R2):
    //  0..8MB   : h   (GNN)   -> Kc0(0..4), Kc1(4..8)  (attn)
    //  8..16MB  : h2  (GNN)   -> Kc2(8..12), Vt0(12..16)
    // 16..40MB  : qkv (live through attn)
    // 40..48MB  : aO
    // 48..56MB  : tmp (post-attn gemm)
    // 56MB..    : rowp, curs, esrc
    float* h    = (float*)(ws + 0);
    float* h2   = (float*)(ws + (8u  << 20));
    float* qkv  = (float*)(ws + (16u << 20));
    float* aO   = (float*)(ws + (40u << 20));
    float* tmp  = (float*)(ws + (48u << 20));
    unsigned short* Kc0 = (unsigned short*)(ws + 0);
    unsigned short* Kc1 = (unsigned short*)(ws + (4u  << 20));
    unsigned short* Kc2 = (unsigned short*)(ws + (8u  << 20));
    unsigned short* Vt0 = (unsigned short*)(ws + (12u << 20));
    int* rowp = (int*)(ws + (56u << 20));
    int* curs = (int*)(ws + (56u << 20) + 40960);
    int* esrc = (int*)(ws + (56u << 20) + 81920);

    // CSR build
    hipMemsetAsync(curs, 0, N_NODES * sizeof(int), stream);
    hist_kernel<<<NEDGE / 256, 256, 0, stream>>>(ei, curs);
    scan_kernel<<<1, 1024, 0, stream>>>(curs, rowp, curs);
    scatter_kernel<<<NEDGE / 256, 256, 0, stream>>>(ei, curs, esrc);

    // input projection
    gemm_bias_kernel<<<dim3(N_NODES / 64, HID / 64), 256, 0, stream>>>(
        x, W_in, b_in, h, N_NODES, HID, IND);

    // 3 GNN layers
    aggregate_kernel<<<N_NODES, 256, 0, stream>>>(h,  h2, rowp, esrc, plas, syn, 0);
    aggregate_kernel<<<N_NODES, 256, 0, stream>>>(h2, h,  rowp, esrc, plas, syn, 1);
    aggregate_kernel<<<N_NODES, 256, 0, stream>>>(h,  h2, rowp, esrc, plas, syn, 2);

    // qkv projection
    gemm_bias_kernel<<<dim3(N_NODES / 64, 768 / 64), 256, 0, stream>>>(
        h2, inpw, inpb, qkv, N_NODES, 768, HID);

    // split pre-pass
    split_kernel<<<dim3(N_NODES / 64, NHEAD), 256, 0, stream>>>(
        qkv, Kc0, Kc1, Kc2, Vt0);

    // MFMA attention (128 q-rows/block)
    attn_mfma_kernel<<<dim3(N_NODES / 128, NHEAD), 256, 0, stream>>>(
        qkv, Kc0, Kc1, Kc2, Vt0, aO);

    // output projections
    gemm_bias_kernel<<<dim3(N_NODES / 64, HID / 64), 256, 0, stream>>>(
        aO, outpw, outpb, tmp, N_NODES, HID, HID);
    gemm_bias_kernel<<<dim3(N_NODES / 64, OUTD / 64), 256, 0, stream>>>(
        tmp, Wout, bout, out, N_NODES, OUTD, HID);
}

// Round 4
// 610.704 us; speedup vs baseline: 2.9898x; 1.1323x over previous
//
#include <hip/hip_runtime.h>
#include <hip/hip_bf16.h>
#include <float.h>

#define N_NODES 8192
#define NEDGE   524288
#define IND     128
#define HID     256
#define OUTD    128
#define NHEAD   4
#define HD      64

typedef short short8 __attribute__((ext_vector_type(8)));
typedef float f32x4  __attribute__((ext_vector_type(4)));
typedef float f32x16 __attribute__((ext_vector_type(16)));
typedef unsigned int u32x4 __attribute__((ext_vector_type(4)));

__device__ __forceinline__ float sigmoidf_(float x) { return 1.0f / (1.0f + expf(-x)); }

__device__ __forceinline__ unsigned short f2bf(float f) {
    __hip_bfloat16 b = __float2bfloat16(f);
    return __builtin_bit_cast(unsigned short, b);
}
__device__ __forceinline__ float bf2f(unsigned short u) {
    __hip_bfloat16 b = __builtin_bit_cast(__hip_bfloat16, u);
    return __bfloat162float(b);
}
__device__ __forceinline__ void split3(float x, unsigned short& a, unsigned short& b, unsigned short& c) {
    a = f2bf(x); float r = x - bf2f(a);
    b = f2bf(r); r = r - bf2f(b);
    c = f2bf(r);
}
// pack two f32 -> 2 bf16 in one u32 (RNE)
__device__ __forceinline__ unsigned int cvtpk(float lo, float hi) {
    unsigned int r;
    asm("v_cvt_pk_bf16_f32 %0, %1, %2" : "=v"(r) : "v"(lo), "v"(hi));
    return r;
}
// a' = (a.low | b.low->hi half swap): a.lanes[32:63] <-> b.lanes[0:31]
__device__ __forceinline__ void plswap(unsigned int& a, unsigned int& b) {
    asm volatile("v_permlane32_swap_b32 %0, %1" : "+v"(a), "+v"(b));
}

__device__ __forceinline__ void gll16(const void* g, void* l) {
    __builtin_amdgcn_global_load_lds(
        (const __attribute__((address_space(1))) void*)g,
        (__attribute__((address_space(3))) void*)l, 16, 0, 0);
}

__device__ __forceinline__ f32x16 mfma32(short8 a, short8 b, f32x16 c) {
    return __builtin_amdgcn_mfma_f32_32x32x16_bf16(a, b, c, 0, 0, 0);
}

// ---------------- generic C[M,N] = A[M,K] * W[N,K]^T + bias ----------------
__global__ __launch_bounds__(256) void gemm_bias_kernel(
    const float* __restrict__ A, const float* __restrict__ W,
    const float* __restrict__ bias, float* __restrict__ C,
    int M, int Nn, int K)
{
    __shared__ float As[64][33];
    __shared__ float Ws[64][33];
    const int t  = threadIdx.x;
    const int tx = t & 15, ty = t >> 4;
    const int m0 = blockIdx.x * 64, n0 = blockIdx.y * 64;
    const int lr = t >> 2;
    const int lc = (t & 3) * 8;

    float acc[4][4] = {};
    for (int kk = 0; kk < K; kk += 32) {
        const float* Ap = A + (size_t)(m0 + lr) * K + kk + lc;
        const float* Wp = W + (size_t)(n0 + lr) * K + kk + lc;
        float4 a0 = *(const float4*)(Ap);
        float4 a1 = *(const float4*)(Ap + 4);
        float4 w0 = *(const float4*)(Wp);
        float4 w1 = *(const float4*)(Wp + 4);
        __syncthreads();
        As[lr][lc + 0] = a0.x; As[lr][lc + 1] = a0.y; As[lr][lc + 2] = a0.z; As[lr][lc + 3] = a0.w;
        As[lr][lc + 4] = a1.x; As[lr][lc + 5] = a1.y; As[lr][lc + 6] = a1.z; As[lr][lc + 7] = a1.w;
        Ws[lr][lc + 0] = w0.x; Ws[lr][lc + 1] = w0.y; Ws[lr][lc + 2] = w0.z; Ws[lr][lc + 3] = w0.w;
        Ws[lr][lc + 4] = w1.x; Ws[lr][lc + 5] = w1.y; Ws[lr][lc + 6] = w1.z; Ws[lr][lc + 7] = w1.w;
        __syncthreads();
        #pragma unroll 8
        for (int k = 0; k < 32; ++k) {
            float a[4], w[4];
            #pragma unroll
            for (int i = 0; i < 4; ++i) a[i] = As[ty * 4 + i][k];
            #pragma unroll
            for (int j = 0; j < 4; ++j) w[j] = Ws[tx * 4 + j][k];
            #pragma unroll
            for (int i = 0; i < 4; ++i)
                #pragma unroll
                for (int j = 0; j < 4; ++j)
                    acc[i][j] += a[i] * w[j];
        }
    }
    #pragma unroll
    for (int i = 0; i < 4; ++i) {
        const int m = m0 + ty * 4 + i;
        #pragma unroll
        for (int j = 0; j < 4; ++j) {
            const int n = n0 + tx * 4 + j;
            C[(size_t)m * Nn + n] = acc[i][j] + bias[n];
        }
    }
}

// ---------------- CSR build ----------------
__global__ void hist_kernel(const int* __restrict__ ei, int* __restrict__ deg)
{
    int e = blockIdx.x * blockDim.x + threadIdx.x;
    if (e < NEDGE) atomicAdd(&deg[ei[NEDGE + e]], 1);
}

__global__ __launch_bounds__(1024) void scan_kernel(
    const int* __restrict__ deg, int* __restrict__ row_ptr, int* __restrict__ cursor)
{
    __shared__ int sh[1024];
    const int t = threadIdx.x;
    int v[8]; int s = 0;
    #pragma unroll
    for (int i = 0; i < 8; ++i) { v[i] = deg[t * 8 + i]; s += v[i]; }
    sh[t] = s; __syncthreads();
    for (int off = 1; off < 1024; off <<= 1) {
        int add = (t >= off) ? sh[t - off] : 0;
        __syncthreads();
        sh[t] += add;
        __syncthreads();
    }
    int base = sh[t] - s;
    #pragma unroll
    for (int i = 0; i < 8; ++i) {
        row_ptr[t * 8 + i] = base;
        cursor[t * 8 + i]  = base;
        base += v[i];
    }
    if (t == 1023) row_ptr[N_NODES] = base;
}

__global__ void scatter_kernel(const int* __restrict__ ei, int* __restrict__ cursor,
                               int* __restrict__ esrc)
{
    int e = blockIdx.x * blockDim.x + threadIdx.x;
    if (e < NEDGE) {
        int d = ei[NEDGE + e];
        int p = atomicAdd(&cursor[d], 1);
        esrc[p] = ei[e];
    }
}

// ---------------- GNN aggregate ----------------
__global__ __launch_bounds__(256) void aggregate_kernel(
    const float* __restrict__ hin, float* __restrict__ hout,
    const int* __restrict__ row_ptr, const int* __restrict__ esrc,
    const float* __restrict__ plas, const float* __restrict__ syn, int layer)
{
    const int b = blockIdx.x;
    const int c = threadIdx.x;
    const int st = row_ptr[b], en = row_ptr[b + 1];
    float a0 = 0.f, a1 = 0.f, a2 = 0.f, a3 = 0.f;
    int e = st;
    for (; e + 4 <= en; e += 4) {
        int s0 = esrc[e], s1 = esrc[e + 1], s2 = esrc[e + 2], s3 = esrc[e + 3];
        a0 += hin[(size_t)s0 * HID + c];
        a1 += hin[(size_t)s1 * HID + c];
        a2 += hin[(size_t)s2 * HID + c];
        a3 += hin[(size_t)s3 * HID + c];
    }
    float acc = (a0 + a1) + (a2 + a3);
    for (; e < en; ++e) acc += hin[(size_t)esrc[e] * HID + c];
    const float scale = sigmoidf_(plas[layer]) * sigmoidf_(syn[layer]);
    float x = acc * scale;
    hout[(size_t)b * HID + c] = (x > 0.f) ? x : 0.01f * x;
}

// ---------------- pre-pass: split K (3 bf16 comps), V (1 comp, transposed)
// Kc layout: [head][n][64] bf16, 16B-chunk j stored at j ^ ((n>>2)&7).
// Vt layout: [head][64 d][8192 n] bf16, within each 64-n group chunk nc stored at nc ^ ((d>>2)&7).
__global__ __launch_bounds__(256) void split_kernel(
    const float* __restrict__ qkv,
    unsigned short* __restrict__ Kc0, unsigned short* __restrict__ Kc1,
    unsigned short* __restrict__ Kc2, unsigned short* __restrict__ Vt0)
{
    __shared__ unsigned short vts[64 * 80];
    const int h  = blockIdx.y;
    const int n0 = blockIdx.x * 64;
    const int t  = threadIdx.x;
    const int r  = t >> 2;          // node row 0..63
    const int n  = n0 + r;
    const int dc = (t & 3) * 16;    // d-col start

    // K split (3 comps)
    {
        const float* kp = qkv + (size_t)n * 768 + 256 + h * 64 + dc;
        float kv[16];
        #pragma unroll
        for (int i = 0; i < 16; i += 4) {
            float4 f = *(const float4*)(kp + i);
            kv[i] = f.x; kv[i+1] = f.y; kv[i+2] = f.z; kv[i+3] = f.w;
        }
        #pragma unroll
        for (int half = 0; half < 2; ++half) {
            short8 c0, c1, c2;
            #pragma unroll
            for (int j = 0; j < 8; ++j) {
                unsigned short a, b, c;
                split3(kv[half * 8 + j], a, b, c);
                c0[j] = (short)a; c1[j] = (short)b; c2[j] = (short)c;
            }
            const int pos = ((dc >> 3) + half) ^ ((n >> 2) & 7);
            const size_t base = ((size_t)(h * 8192 + n)) * 64 + pos * 8;
            *(short8*)(Kc0 + base) = c0;
            *(short8*)(Kc1 + base) = c1;
            *(short8*)(Kc2 + base) = c2;
        }
    }
    // V -> bf16, transpose via LDS
    {
        const float* vp = qkv + (size_t)n * 768 + 512 + h * 64 + dc;
        #pragma unroll
        for (int i = 0; i < 16; i += 4) {
            float4 f = *(const float4*)(vp + i);
            float vv[4] = {f.x, f.y, f.z, f.w};
            #pragma unroll
            for (int k2 = 0; k2 < 4; ++k2)
                vts[(dc + i + k2) * 80 + r] = f2bf(vv[k2]);
        }
    }
    __syncthreads();
    // write Vt rows (coalesced 16B chunks, swizzled by (d>>2)&7)
    #pragma unroll
    for (int i = 0; i < 2; ++i) {
        const int q = t * 2 + i;            // 0..511: d(64) x nc(8)
        const int d = q >> 3, nc = q & 7;
        short8 vv = *(const short8*)(&vts[d * 80 + nc * 8]);
        const size_t dst = ((size_t)(h * 64 + d)) * 8192 + n0 + ((nc ^ ((d >> 2) & 7)) * 8);
        *(short8*)(Vt0 + dst) = vv;
    }
}

// ---------------- MFMA flash attention: 32x32, q=64/wave, split-K x2, dbuf ----------------
// 4 waves/block, 256 q/block. grid (32, 4 heads, 2 halves) = 256 blocks.
// LDS: 2 buffers x (K 3comps 24KB + V 8KB) = 64KB. P stays in registers (cvt_pk + permlane32_swap).
__global__ __launch_bounds__(256, 1) void attn_mfma_kernel(
    const float* __restrict__ qkv,
    const unsigned short* __restrict__ Kc0, const unsigned short* __restrict__ Kc1,
    const unsigned short* __restrict__ Kc2, const unsigned short* __restrict__ Vt0,
    float* __restrict__ Op, float* __restrict__ Ml)
{
    __shared__ __align__(16) char smem[65536];
    const int h    = blockIdx.y;
    const int half = blockIdx.z;
    const int n0   = blockIdx.x * 256;
    const int t    = threadIdx.x;
    const int wv   = t >> 6;
    const int lane = t & 63;
    const int l31  = lane & 31, l5 = lane >> 5;
    const int qbase = n0 + wv * 64;

    // ---- Q load + 3-way split (pre-scaled by 1/sqrt(HD)=0.125); B-frag 32x32x16:
    // col(q) = lane&31, k(d) = ks*16 + (lane>>5)*8 + j
    short8 qf[2][3][4];
    #pragma unroll
    for (int qb = 0; qb < 2; ++qb) {
        #pragma unroll
        for (int ks = 0; ks < 4; ++ks) {
            const float* qp = qkv + (size_t)(qbase + qb * 32 + l31) * 768 + h * 64 + ks * 16 + l5 * 8;
            float4 qa = *(const float4*)qp, qb4 = *(const float4*)(qp + 4);
            float qv[8] = {qa.x, qa.y, qa.z, qa.w, qb4.x, qb4.y, qb4.z, qb4.w};
            #pragma unroll
            for (int j = 0; j < 8; ++j) {
                unsigned short a, b, c;
                split3(qv[j] * 0.125f, a, b, c);
                qf[qb][0][ks][j] = (short)a;
                qf[qb][1][ks][j] = (short)b;
                qf[qb][2][ks][j] = (short)c;
            }
        }
    }

    // ---- staging: wave wv stages component wv (Kc0..2, Vt); 8 x 1KB segments
    const unsigned short* cbase = (wv == 0) ? Kc0 : (wv == 1) ? Kc1 : (wv == 2) ? Kc2 : Vt0;
    const char* sgb[8];
    #pragma unroll
    for (int s = 0; s < 8; ++s) {
        const int row = s * 8 + (lane >> 3);
        if (wv < 3)
            sgb[s] = (const char*)(cbase + ((size_t)(h * 8192 + row)) * 64 + (lane & 7) * 8);
        else
            sgb[s] = (const char*)(cbase + ((size_t)(h * 64 + row)) * 8192 + (lane & 7) * 8);
    }
    const size_t ktstride = (wv < 3) ? 8192 : 128;   // bytes per 64-key tile step
    const int ldsbase = wv * 8192;                   // comp offset (Vt -> 24576)

    auto STAGE = [&](int ktg, int bb) {
        #pragma unroll
        for (int s = 0; s < 8; ++s)
            gll16(sgb[s] + (size_t)ktg * ktstride, &smem[bb * 32768 + ldsbase + s * 1024]);
    };

    f32x16 o[2][2];   // [db][qb]
    #pragma unroll
    for (int db = 0; db < 2; ++db)
        #pragma unroll
        for (int qb = 0; qb < 2; ++qb)
            #pragma unroll
            for (int r = 0; r < 16; ++r) o[db][qb][r] = 0.f;
    float mr[2] = {-FLT_MAX, -FLT_MAX};
    float ls[2] = {0.f, 0.f};

    const int kt0 = half * 64;
    STAGE(kt0, 0);
    __syncthreads();

    for (int kt = 0; kt < 64; ++kt) {
        const int bb = kt & 1;
        if (kt < 63) STAGE(kt0 + kt + 1, bb ^ 1);   // issue early; hides under compute
        const char* buf = &smem[bb * 32768];

        // ---- QK^T (S^T[key][q]): A = K comps (row=key), B = Q comps; 6-term split
        f32x16 s[2][2];  // [kb][qb]
        #pragma unroll
        for (int kb = 0; kb < 2; ++kb)
            #pragma unroll
            for (int qb = 0; qb < 2; ++qb)
                #pragma unroll
                for (int r = 0; r < 16; ++r) s[kb][qb][r] = 0.f;

        #pragma unroll
        for (int ks = 0; ks < 4; ++ks) {
            #pragma unroll
            for (int kb = 0; kb < 2; ++kb) {
                const int key = kb * 32 + l31;
                const int off = key * 128 + (((ks * 2 + l5) ^ ((key >> 2) & 7)) * 16);
                short8 k0 = *(const short8*)(buf + off);
                short8 k1 = *(const short8*)(buf + 8192 + off);
                short8 k2 = *(const short8*)(buf + 16384 + off);
                #pragma unroll
                for (int qb = 0; qb < 2; ++qb) {
                    f32x16 acc = s[kb][qb];
                    acc = mfma32(k0, qf[qb][2][ks], acc);
                    acc = mfma32(k1, qf[qb][1][ks], acc);
                    acc = mfma32(k2, qf[qb][0][ks], acc);
                    acc = mfma32(k0, qf[qb][1][ks], acc);
                    acc = mfma32(k1, qf[qb][0][ks], acc);
                    acc = mfma32(k0, qf[qb][0][ks], acc);
                    s[kb][qb] = acc;
                }
            }
        }

        // ---- online softmax (q = lane&31 lane-local; partner = lane^32) + pack P to B-frags
        short8 pb[2][4];  // [qb][kstep]
        #pragma unroll
        for (int qb = 0; qb < 2; ++qb) {
            float mx = s[0][qb][0];
            #pragma unroll
            for (int r = 1; r < 16; ++r) mx = fmaxf(mx, s[0][qb][r]);
            #pragma unroll
            for (int r = 0; r < 16; ++r) mx = fmaxf(mx, s[1][qb][r]);
            mx = fmaxf(mx, __shfl_xor(mx, 32));
            const float mn = fmaxf(mr[qb], mx);
            const float alpha = __expf(mr[qb] - mn);
            mr[qb] = mn;
            float ps = 0.f;
            #pragma unroll
            for (int kb = 0; kb < 2; ++kb)
                #pragma unroll
                for (int r = 0; r < 16; ++r) {
                    float p = __expf(s[kb][qb][r] - mn);
                    s[kb][qb][r] = p;
                    ps += p;
                }
            ps += __shfl_xor(ps, 32);
            ls[qb] = ls[qb] * alpha + ps;
            o[0][qb] *= alpha;
            o[1][qb] *= alpha;

            // pack: global kstep ks covers keys 16ks..16ks+15; kb = ks>>1, reg base rb = 8*(ks&1).
            // C-reg r: key = kb*32 + (r&3) + 8*(r>>2) + 4*l5.
            // After plswap(A,B): A' = j0..3 word, B' = j4..7 word for both lane halves.
            #pragma unroll
            for (int ks = 0; ks < 4; ++ks) {
                const int kb = ks >> 1, rb = (ks & 1) * 8;
                unsigned int A0 = cvtpk(s[kb][qb][rb + 0], s[kb][qb][rb + 1]);
                unsigned int A1 = cvtpk(s[kb][qb][rb + 2], s[kb][qb][rb + 3]);
                unsigned int B0 = cvtpk(s[kb][qb][rb + 4], s[kb][qb][rb + 5]);
                unsigned int B1 = cvtpk(s[kb][qb][rb + 6], s[kb][qb][rb + 7]);
                plswap(A0, B0);
                plswap(A1, B1);
                u32x4 pw; pw[0] = A0; pw[1] = A1; pw[2] = B0; pw[3] = B1;
                pb[qb][ks] = __builtin_bit_cast(short8, pw);
            }
        }

        // ---- PV: O^T[d][q] += V^T[d][k] P^T[k][q]  (single bf16 term)
        #pragma unroll
        for (int ks = 0; ks < 4; ++ks) {
            #pragma unroll
            for (int db = 0; db < 2; ++db) {
                const int d = db * 32 + l31;
                const int off = 24576 + d * 128 + (((ks * 2 + l5) ^ ((d >> 2) & 7)) * 16);
                short8 v = *(const short8*)(buf + off);
                o[db][0] = mfma32(v, pb[0][ks], o[db][0]);
                o[db][1] = mfma32(v, pb[1][ks], o[db][1]);
            }
        }

        __syncthreads();   // implies vmcnt(0): next-tile staging (issued pre-compute) has landed
    }

    // ---- epilogue: partial O (unnormalized) + m,l
    #pragma unroll
    for (int qb = 0; qb < 2; ++qb) {
        const int q = qbase + qb * 32 + l31;
        float* opq = Op + ((size_t)((half * 4 + h) * 8192 + q)) * 64;
        #pragma unroll
        for (int db = 0; db < 2; ++db) {
            #pragma unroll
            for (int tq = 0; tq < 4; ++tq) {
                float4 st = { o[db][qb][4 * tq + 0], o[db][qb][4 * tq + 1],
                              o[db][qb][4 * tq + 2], o[db][qb][4 * tq + 3] };
                *(float4*)(opq + db * 32 + tq * 8 + l5 * 4) = st;
            }
        }
        if (l5 == 0) {
            Ml[((size_t)(half * 4 + h) * 2 + 0) * 8192 + q] = mr[qb];
            Ml[((size_t)(half * 4 + h) * 2 + 1) * 8192 + q] = ls[qb];
        }
    }
}

// ---------------- split-K combine: aO = (c0*O0 + c1*O1) / (c0*l0 + c1*l1) ----------------
__global__ __launch_bounds__(256) void combine_kernel(
    const float* __restrict__ Op, const float* __restrict__ Ml, float* __restrict__ aO)
{
    const int idx = blockIdx.x * 256 + threadIdx.x;   // 0..131071
    const int c = idx & 3;
    const int q = (idx >> 2) & 8191;
    const int h = idx >> 15;
    const float m0 = Ml[((size_t)(0 + h) * 2 + 0) * 8192 + q];
    const float l0 = Ml[((size_t)(0 + h) * 2 + 1) * 8192 + q];
    const float m1 = Ml[((size_t)(4 + h) * 2 + 0) * 8192 + q];
    const float l1 = Ml[((size_t)(4 + h) * 2 + 1) * 8192 + q];
    const float m  = fmaxf(m0, m1);
    const float c0 = __expf(m0 - m), c1 = __expf(m1 - m);
    const float inv = 1.f / (l0 * c0 + l1 * c1);
    const float* p0 = Op + ((size_t)(0 + h) * 8192 + q) * 64 + c * 16;
    const float* p1 = Op + ((size_t)(4 + h) * 8192 + q) * 64 + c * 16;
    float* dst = aO + (size_t)q * 256 + h * 64 + c * 16;
    #pragma unroll
    for (int i = 0; i < 4; ++i) {
        float4 a = *(const float4*)(p0 + i * 4);
        float4 b = *(const float4*)(p1 + i * 4);
        float4 r = { (a.x * c0 + b.x * c1) * inv, (a.y * c0 + b.y * c1) * inv,
                     (a.z * c0 + b.z * c1) * inv, (a.w * c0 + b.w * c1) * inv };
        *(float4*)(dst + i * 4) = r;
    }
}

// ---------------- launch ----------------
extern "C" void kernel_launch(void* const* d_in, const int* in_sizes, int n_in,
                              void* d_out, int out_size, void* d_ws, size_t ws_size,
                              hipStream_t stream)
{
    const float* x     = (const float*)d_in[0];
    const int*   ei    = (const int*)  d_in[1];
    const float* W_in  = (const float*)d_in[2];
    const float* b_in  = (const float*)d_in[3];
    const float* plas  = (const float*)d_in[4];
    const float* syn   = (const float*)d_in[5];
    const float* inpw  = (const float*)d_in[6];
    const float* inpb  = (const float*)d_in[7];
    const float* outpw = (const float*)d_in[8];
    const float* outpb = (const float*)d_in[9];
    const float* Wout  = (const float*)d_in[10];
    const float* bout  = (const float*)d_in[11];
    float* out = (float*)d_out;

    char* ws = (char*)d_ws;
    // layout (58.1 MiB, unchanged footprint):
    //  0..8MB   : h   (GNN)  -> Kc0(0..4), Kc1(4..8) (attn)  -> aO (combine output)
    //  8..16MB  : h2  (GNN)  -> Kc2(8..12), Vt0(12..16)
    // 16..40MB  : qkv (live through attn)
    // 40..48MB  : Op half0
    // 48..56MB  : Op half1  -> tmp (post-attn gemm)
    // 56MB..    : rowp, curs, esrc (-> Ml during attn)
    float* h    = (float*)(ws + 0);
    float* h2   = (float*)(ws + (8u  << 20));
    float* qkv  = (float*)(ws + (16u << 20));
    float* Op   = (float*)(ws + (40u << 20));
    float* aO   = (float*)(ws + 0);
    float* tmp  = (float*)(ws + (48u << 20));
    unsigned short* Kc0 = (unsigned short*)(ws + 0);
    unsigned short* Kc1 = (unsigned short*)(ws + (4u  << 20));
    unsigned short* Kc2 = (unsigned short*)(ws + (8u  << 20));
    unsigned short* Vt0 = (unsigned short*)(ws + (12u << 20));
    int*   rowp = (int*)(ws + (56u << 20));
    int*   curs = (int*)(ws + (56u << 20) + 40960);
    int*   esrc = (int*)(ws + (56u << 20) + 81920);
    float* Ml   = (float*)(ws + (56u << 20) + 81920);   // reuses esrc (dead after aggregates)

    // CSR build
    hipMemsetAsync(curs, 0, N_NODES * sizeof(int), stream);
    hist_kernel<<<NEDGE / 256, 256, 0, stream>>>(ei, curs);
    scan_kernel<<<1, 1024, 0, stream>>>(curs, rowp, curs);
    scatter_kernel<<<NEDGE / 256, 256, 0, stream>>>(ei, curs, esrc);

    // input projection
    gemm_bias_kernel<<<dim3(N_NODES / 64, HID / 64), 256, 0, stream>>>(
        x, W_in, b_in, h, N_NODES, HID, IND);

    // 3 GNN layers
    aggregate_kernel<<<N_NODES, 256, 0, stream>>>(h,  h2, rowp, esrc, plas, syn, 0);
    aggregate_kernel<<<N_NODES, 256, 0, stream>>>(h2, h,  rowp, esrc, plas, syn, 1);
    aggregate_kernel<<<N_NODES, 256, 0, stream>>>(h,  h2, rowp, esrc, plas, syn, 2);

    // qkv projection
    gemm_bias_kernel<<<dim3(N_NODES / 64, 768 / 64), 256, 0, stream>>>(
        h2, inpw, inpb, qkv, N_NODES, 768, HID);

    // split pre-pass
    split_kernel<<<dim3(N_NODES / 64, NHEAD), 256, 0, stream>>>(
        qkv, Kc0, Kc1, Kc2, Vt0);

    // MFMA attention: 256 q/block, split-K x2
    attn_mfma_kernel<<<dim3(N_NODES / 256, NHEAD, 2), 256, 0, stream>>>(
        qkv, Kc0, Kc1, Kc2, Vt0, Op, Ml);

    // combine halves
    combine_kernel<<<512, 256, 0, stream>>>(Op, Ml, aO);

    // output projections
    gemm_bias_kernel<<<dim3(N_NODES / 64, HID / 64), 256, 0, stream>>>(
        aO, outpw, outpb, tmp, N_NODES, HID, HID);
    gemm_bias_kernel<<<dim3(N_NODES / 64, OUTD / 64), 256, 0, stream>>>(
        tmp, Wout, bout, out, N_NODES, OUTD, HID);
}

// Round 5
// 590.070 us; speedup vs baseline: 3.0943x; 1.0350x over previous
//
#include <hip/hip_runtime.h>
#include <hip/hip_bf16.h>
#include <float.h>

#define N_NODES 8192
#define NEDGE   524288
#define IND     128
#define HID     256
#define OUTD    128
#define NHEAD   4
#define HD      64

typedef short short8 __attribute__((ext_vector_type(8)));
typedef float f32x4  __attribute__((ext_vector_type(4)));
typedef float f32x16 __attribute__((ext_vector_type(16)));
typedef unsigned int u32x4 __attribute__((ext_vector_type(4)));

__device__ __forceinline__ float sigmoidf_(float x) { return 1.0f / (1.0f + expf(-x)); }

__device__ __forceinline__ unsigned short f2bf(float f) {
    __hip_bfloat16 b = __float2bfloat16(f);
    return __builtin_bit_cast(unsigned short, b);
}
__device__ __forceinline__ float bf2f(unsigned short u) {
    __hip_bfloat16 b = __builtin_bit_cast(__hip_bfloat16, u);
    return __bfloat162float(b);
}
__device__ __forceinline__ void split3(float x, unsigned short& a, unsigned short& b, unsigned short& c) {
    a = f2bf(x); float r = x - bf2f(a);
    b = f2bf(r); r = r - bf2f(b);
    c = f2bf(r);
}
__device__ __forceinline__ unsigned int cvtpk(float lo, float hi) {
    unsigned int r;
    asm("v_cvt_pk_bf16_f32 %0, %1, %2" : "=v"(r) : "v"(lo), "v"(hi));
    return r;
}
__device__ __forceinline__ void plswap(unsigned int& a, unsigned int& b) {
    asm volatile("v_permlane32_swap_b32 %0, %1" : "+v"(a), "+v"(b));
}
__device__ __forceinline__ void gll16(const void* g, void* l) {
    __builtin_amdgcn_global_load_lds(
        (const __attribute__((address_space(1))) void*)g,
        (__attribute__((address_space(3))) void*)l, 16, 0, 0);
}
__device__ __forceinline__ f32x16 mfma32(short8 a, short8 b, f32x16 c) {
    return __builtin_amdgcn_mfma_f32_32x32x16_bf16(a, b, c, 0, 0, 0);
}

// ---------------- C[M,N] = A[M,K] * W[N,K]^T + bias; 128x64 tile, 8x4/thread ----------------
__global__ __launch_bounds__(256) void gemm_bias_kernel(
    const float* __restrict__ A, const float* __restrict__ W,
    const float* __restrict__ bias, float* __restrict__ C,
    int M, int Nn, int K)
{
    __shared__ float As[128][33];
    __shared__ float Ws[64][33];
    const int t  = threadIdx.x;
    const int tx = t & 15, ty = t >> 4;
    const int m0 = blockIdx.x * 128, n0 = blockIdx.y * 64;
    const int alr = t >> 1, alc = (t & 1) * 16;
    const int wlr = t >> 2, wlc = (t & 3) * 8;

    float acc[8][4] = {};
    for (int kk = 0; kk < K; kk += 32) {
        const float* Ap = A + (size_t)(m0 + alr) * K + kk + alc;
        const float* Wp = W + (size_t)(n0 + wlr) * K + kk + wlc;
        float4 a0 = *(const float4*)(Ap);
        float4 a1 = *(const float4*)(Ap + 4);
        float4 a2 = *(const float4*)(Ap + 8);
        float4 a3 = *(const float4*)(Ap + 12);
        float4 w0 = *(const float4*)(Wp);
        float4 w1 = *(const float4*)(Wp + 4);
        __syncthreads();
        *(float4*)(&As[alr][alc + 0])  = a0;
        *(float4*)(&As[alr][alc + 4])  = a1;
        *(float4*)(&As[alr][alc + 8])  = a2;
        *(float4*)(&As[alr][alc + 12]) = a3;
        *(float4*)(&Ws[wlr][wlc + 0])  = w0;
        *(float4*)(&Ws[wlr][wlc + 4])  = w1;
        __syncthreads();
        #pragma unroll 4
        for (int k = 0; k < 32; ++k) {
            float a[8], w[4];
            #pragma unroll
            for (int i = 0; i < 8; ++i) a[i] = As[ty * 8 + i][k];
            #pragma unroll
            for (int j = 0; j < 4; ++j) w[j] = Ws[tx * 4 + j][k];
            #pragma unroll
            for (int i = 0; i < 8; ++i)
                #pragma unroll
                for (int j = 0; j < 4; ++j)
                    acc[i][j] += a[i] * w[j];
        }
    }
    #pragma unroll
    for (int i = 0; i < 8; ++i) {
        const int m = m0 + ty * 8 + i;
        #pragma unroll
        for (int j = 0; j < 4; ++j) {
            const int n = n0 + tx * 4 + j;
            C[(size_t)m * Nn + n] = acc[i][j] + bias[n];
        }
    }
}

// ---------------- CSR build ----------------
__global__ void hist_kernel(const int* __restrict__ ei, int* __restrict__ deg)
{
    int e = blockIdx.x * blockDim.x + threadIdx.x;
    if (e < NEDGE) atomicAdd(&deg[ei[NEDGE + e]], 1);
}

__global__ __launch_bounds__(1024) void scan_kernel(
    const int* __restrict__ deg, int* __restrict__ row_ptr, int* __restrict__ cursor)
{
    __shared__ int sh[1024];
    const int t = threadIdx.x;
    int v[8]; int s = 0;
    #pragma unroll
    for (int i = 0; i < 8; ++i) { v[i] = deg[t * 8 + i]; s += v[i]; }
    sh[t] = s; __syncthreads();
    for (int off = 1; off < 1024; off <<= 1) {
        int add = (t >= off) ? sh[t - off] : 0;
        __syncthreads();
        sh[t] += add;
        __syncthreads();
    }
    int base = sh[t] - s;
    #pragma unroll
    for (int i = 0; i < 8; ++i) {
        row_ptr[t * 8 + i] = base;
        cursor[t * 8 + i]  = base;
        base += v[i];
    }
    if (t == 1023) row_ptr[N_NODES] = base;
}

__global__ void scatter_kernel(const int* __restrict__ ei, int* __restrict__ cursor,
                               int* __restrict__ esrc)
{
    int e = blockIdx.x * blockDim.x + threadIdx.x;
    if (e < NEDGE) {
        int d = ei[NEDGE + e];
        int p = atomicAdd(&cursor[d], 1);
        esrc[p] = ei[e];
    }
}

// ---------------- GNN aggregate ----------------
__global__ __launch_bounds__(256) void aggregate_kernel(
    const float* __restrict__ hin, float* __restrict__ hout,
    const int* __restrict__ row_ptr, const int* __restrict__ esrc,
    const float* __restrict__ plas, const float* __restrict__ syn, int layer)
{
    const int b = blockIdx.x;
    const int c = threadIdx.x;
    const int st = row_ptr[b], en = row_ptr[b + 1];
    float a0 = 0.f, a1 = 0.f, a2 = 0.f, a3 = 0.f;
    int e = st;
    for (; e + 4 <= en; e += 4) {
        int s0 = esrc[e], s1 = esrc[e + 1], s2 = esrc[e + 2], s3 = esrc[e + 3];
        a0 += hin[(size_t)s0 * HID + c];
        a1 += hin[(size_t)s1 * HID + c];
        a2 += hin[(size_t)s2 * HID + c];
        a3 += hin[(size_t)s3 * HID + c];
    }
    float acc = (a0 + a1) + (a2 + a3);
    for (; e < en; ++e) acc += hin[(size_t)esrc[e] * HID + c];
    const float scale = sigmoidf_(plas[layer]) * sigmoidf_(syn[layer]);
    float x = acc * scale;
    hout[(size_t)b * HID + c] = (x > 0.f) ? x : 0.01f * x;
}

// ---------------- pre-pass: split K (3 bf16 comps), V (1 comp, transposed)
// Kc: [head][n][64] bf16, 16B-chunk j stored at j ^ (n&7).
// Vt: [head][64 d][8192 n] bf16, within 64-n group chunk nc stored at nc ^ (d&7).
__global__ __launch_bounds__(256) void split_kernel(
    const float* __restrict__ qkv,
    unsigned short* __restrict__ Kc0, unsigned short* __restrict__ Kc1,
    unsigned short* __restrict__ Kc2, unsigned short* __restrict__ Vt0)
{
    __shared__ unsigned short vts[64 * 80];
    const int h  = blockIdx.y;
    const int n0 = blockIdx.x * 64;
    const int t  = threadIdx.x;
    const int r  = t >> 2;
    const int n  = n0 + r;
    const int dc = (t & 3) * 16;

    {
        const float* kp = qkv + (size_t)n * 768 + 256 + h * 64 + dc;
        float kv[16];
        #pragma unroll
        for (int i = 0; i < 16; i += 4) {
            float4 f = *(const float4*)(kp + i);
            kv[i] = f.x; kv[i+1] = f.y; kv[i+2] = f.z; kv[i+3] = f.w;
        }
        #pragma unroll
        for (int half = 0; half < 2; ++half) {
            short8 c0, c1, c2;
            #pragma unroll
            for (int j = 0; j < 8; ++j) {
                unsigned short a, b, c;
                split3(kv[half * 8 + j], a, b, c);
                c0[j] = (short)a; c1[j] = (short)b; c2[j] = (short)c;
            }
            const int pos = ((dc >> 3) + half) ^ (n & 7);
            const size_t base = ((size_t)(h * 8192 + n)) * 64 + pos * 8;
            *(short8*)(Kc0 + base) = c0;
            *(short8*)(Kc1 + base) = c1;
            *(short8*)(Kc2 + base) = c2;
        }
    }
    {
        const float* vp = qkv + (size_t)n * 768 + 512 + h * 64 + dc;
        #pragma unroll
        for (int i = 0; i < 16; i += 4) {
            float4 f = *(const float4*)(vp + i);
            float vv[4] = {f.x, f.y, f.z, f.w};
            #pragma unroll
            for (int k2 = 0; k2 < 4; ++k2)
                vts[(dc + i + k2) * 80 + r] = f2bf(vv[k2]);
        }
    }
    __syncthreads();
    #pragma unroll
    for (int i = 0; i < 2; ++i) {
        const int q = t * 2 + i;
        const int d = q >> 3, nc = q & 7;
        short8 vv = *(const short8*)(&vts[d * 80 + nc * 8]);
        const size_t dst = ((size_t)(h * 64 + d)) * 8192 + n0 + ((nc ^ (d & 7)) * 8);
        *(short8*)(Vt0 + dst) = vv;
    }
}

// ---------------- MFMA flash attention: 32x32, q=64/wave, split-K x4, dbuf, 2 blocks/CU --------
// grid (32, 4 heads, 4 quarters) = 512 blocks; 4 waves/block; LDS 64KB -> 2 blocks/CU.
__global__ __launch_bounds__(256, 2) void attn_mfma_kernel(
    const float* __restrict__ qkv,
    const unsigned short* __restrict__ Kc0, const unsigned short* __restrict__ Kc1,
    const unsigned short* __restrict__ Kc2, const unsigned short* __restrict__ Vt0,
    unsigned short* __restrict__ Op16, float* __restrict__ Ml)
{
    __shared__ __align__(16) char smem[65536];
    const int h    = blockIdx.y;
    const int quar = blockIdx.z;
    const int n0   = blockIdx.x * 256;
    const int t    = threadIdx.x;
    const int wv   = t >> 6;
    const int lane = t & 63;
    const int l31  = lane & 31, l5 = lane >> 5;
    const int qbase = n0 + wv * 64;

    // Q load + 3-way split (pre-scaled by 0.125); B-frag: col(q)=lane&31, k = ks*16 + l5*8 + j
    short8 qf[2][3][4];
    #pragma unroll
    for (int qb = 0; qb < 2; ++qb) {
        #pragma unroll
        for (int ks = 0; ks < 4; ++ks) {
            const float* qp = qkv + (size_t)(qbase + qb * 32 + l31) * 768 + h * 64 + ks * 16 + l5 * 8;
            float4 qa = *(const float4*)qp, qb4 = *(const float4*)(qp + 4);
            float qv[8] = {qa.x, qa.y, qa.z, qa.w, qb4.x, qb4.y, qb4.z, qb4.w};
            #pragma unroll
            for (int j = 0; j < 8; ++j) {
                unsigned short a, b, c;
                split3(qv[j] * 0.125f, a, b, c);
                qf[qb][0][ks][j] = (short)a;
                qf[qb][1][ks][j] = (short)b;
                qf[qb][2][ks][j] = (short)c;
            }
        }
    }

    // staging: wave wv stages component wv (Kc0..2, Vt); 8 x 1KB segments
    const unsigned short* cbase = (wv == 0) ? Kc0 : (wv == 1) ? Kc1 : (wv == 2) ? Kc2 : Vt0;
    const char* sgb[8];
    #pragma unroll
    for (int s = 0; s < 8; ++s) {
        const int row = s * 8 + (lane >> 3);
        if (wv < 3)
            sgb[s] = (const char*)(cbase + ((size_t)(h * 8192 + row)) * 64 + (lane & 7) * 8);
        else
            sgb[s] = (const char*)(cbase + ((size_t)(h * 64 + row)) * 8192 + (lane & 7) * 8);
    }
    const size_t ktstride = (wv < 3) ? 8192 : 128;
    const int ldsbase = wv * 8192;

    auto STAGE = [&](int ktg, int bb) {
        #pragma unroll
        for (int s = 0; s < 8; ++s)
            gll16(sgb[s] + (size_t)ktg * ktstride, &smem[bb * 32768 + ldsbase + s * 1024]);
    };

    f32x16 o[2][2];   // [db][qb]
    #pragma unroll
    for (int db = 0; db < 2; ++db)
        #pragma unroll
        for (int qb = 0; qb < 2; ++qb)
            #pragma unroll
            for (int r = 0; r < 16; ++r) o[db][qb][r] = 0.f;
    float mr[2] = {-FLT_MAX, -FLT_MAX};
    float ls[2] = {0.f, 0.f};

    const int kt0 = quar * 32;
    STAGE(kt0, 0);
    __syncthreads();

    for (int kt = 0; kt < 32; ++kt) {
        const int bb = kt & 1;
        if (kt < 31) STAGE(kt0 + kt + 1, bb ^ 1);
        const char* buf = &smem[bb * 32768];

        // ---- QK^T (S^T[key][q]); 6-term split
        f32x16 s[2][2];
        #pragma unroll
        for (int kb = 0; kb < 2; ++kb)
            #pragma unroll
            for (int qb = 0; qb < 2; ++qb)
                #pragma unroll
                for (int r = 0; r < 16; ++r) s[kb][qb][r] = 0.f;

        __builtin_amdgcn_s_setprio(1);
        #pragma unroll
        for (int ks = 0; ks < 4; ++ks) {
            #pragma unroll
            for (int kb = 0; kb < 2; ++kb) {
                const int key = kb * 32 + l31;
                const int off = key * 128 + (((ks * 2 + l5) ^ (key & 7)) * 16);
                short8 k0 = *(const short8*)(buf + off);
                short8 k1 = *(const short8*)(buf + 8192 + off);
                short8 k2 = *(const short8*)(buf + 16384 + off);
                #pragma unroll
                for (int qb = 0; qb < 2; ++qb) {
                    f32x16 acc = s[kb][qb];
                    acc = mfma32(k0, qf[qb][2][ks], acc);
                    acc = mfma32(k1, qf[qb][1][ks], acc);
                    acc = mfma32(k2, qf[qb][0][ks], acc);
                    acc = mfma32(k0, qf[qb][1][ks], acc);
                    acc = mfma32(k1, qf[qb][0][ks], acc);
                    acc = mfma32(k0, qf[qb][0][ks], acc);
                    s[kb][qb] = acc;
                }
            }
        }
        __builtin_amdgcn_s_setprio(0);

        // ---- online softmax with defer-max (THR=8); q = lane&31, partner = lane^32
        short8 pb[2][4];
        #pragma unroll
        for (int qb = 0; qb < 2; ++qb) {
            float mx = s[0][qb][0];
            #pragma unroll
            for (int r = 1; r < 16; ++r) mx = fmaxf(mx, s[0][qb][r]);
            #pragma unroll
            for (int r = 0; r < 16; ++r) mx = fmaxf(mx, s[1][qb][r]);
            mx = fmaxf(mx, __shfl_xor(mx, 32));
            if (__any(mx > mr[qb] + 8.f)) {
                const float mn = fmaxf(mr[qb], mx);
                const float alpha = __expf(mr[qb] - mn);
                mr[qb] = mn;
                ls[qb] *= alpha;
                o[0][qb] *= alpha;
                o[1][qb] *= alpha;
            }
            const float mkeep = mr[qb];
            float ps = 0.f;
            #pragma unroll
            for (int kb = 0; kb < 2; ++kb)
                #pragma unroll
                for (int r = 0; r < 16; ++r) {
                    float p = __expf(s[kb][qb][r] - mkeep);
                    s[kb][qb][r] = p;
                    ps += p;
                }
            ps += __shfl_xor(ps, 32);
            ls[qb] += ps;

            #pragma unroll
            for (int ks = 0; ks < 4; ++ks) {
                const int kb = ks >> 1, rb = (ks & 1) * 8;
                unsigned int A0 = cvtpk(s[kb][qb][rb + 0], s[kb][qb][rb + 1]);
                unsigned int A1 = cvtpk(s[kb][qb][rb + 2], s[kb][qb][rb + 3]);
                unsigned int B0 = cvtpk(s[kb][qb][rb + 4], s[kb][qb][rb + 5]);
                unsigned int B1 = cvtpk(s[kb][qb][rb + 6], s[kb][qb][rb + 7]);
                plswap(A0, B0);
                plswap(A1, B1);
                u32x4 pw; pw[0] = A0; pw[1] = A1; pw[2] = B0; pw[3] = B1;
                pb[qb][ks] = __builtin_bit_cast(short8, pw);
            }
        }

        // ---- PV
        __builtin_amdgcn_s_setprio(1);
        #pragma unroll
        for (int ks = 0; ks < 4; ++ks) {
            #pragma unroll
            for (int db = 0; db < 2; ++db) {
                const int d = db * 32 + l31;
                const int off = 24576 + d * 128 + (((ks * 2 + l5) ^ (d & 7)) * 16);
                short8 v = *(const short8*)(buf + off);
                o[db][0] = mfma32(v, pb[0][ks], o[db][0]);
                o[db][1] = mfma32(v, pb[1][ks], o[db][1]);
            }
        }
        __builtin_amdgcn_s_setprio(0);

        __syncthreads();
    }

    // ---- epilogue: unnormalized partial O (bf16) + m,l
    #pragma unroll
    for (int qb = 0; qb < 2; ++qb) {
        const int q = qbase + qb * 32 + l31;
        unsigned short* opq = Op16 + ((size_t)((quar * 4 + h) * 8192 + q)) * 64;
        #pragma unroll
        for (int db = 0; db < 2; ++db) {
            #pragma unroll
            for (int tq = 0; tq < 4; ++tq) {
                const int d0 = db * 32 + tq * 8 + l5 * 4;
                unsigned int w0 = cvtpk(o[db][qb][4 * tq + 0], o[db][qb][4 * tq + 1]);
                unsigned int w1 = cvtpk(o[db][qb][4 * tq + 2], o[db][qb][4 * tq + 3]);
                uint2 st = {w0, w1};
                *(uint2*)(opq + d0) = st;
            }
        }
        if (l5 == 0) {
            Ml[((size_t)(quar * 4 + h) * 2 + 0) * 8192 + q] = mr[qb];
            Ml[((size_t)(quar * 4 + h) * 2 + 1) * 8192 + q] = ls[qb];
        }
    }
}

// ---------------- split-K combine over 4 partials ----------------
__global__ __launch_bounds__(256) void combine_kernel(
    const unsigned short* __restrict__ Op16, const float* __restrict__ Ml,
    float* __restrict__ aO)
{
    const int idx = blockIdx.x * 256 + threadIdx.x;   // 0..131071
    const int c = idx & 3;
    const int q = (idx >> 2) & 8191;
    const int h = idx >> 15;
    float m[4], l[4];
    float mg = -FLT_MAX;
    #pragma unroll
    for (int s = 0; s < 4; ++s) {
        m[s] = Ml[((size_t)(s * 4 + h) * 2 + 0) * 8192 + q];
        l[s] = Ml[((size_t)(s * 4 + h) * 2 + 1) * 8192 + q];
        mg = fmaxf(mg, m[s]);
    }
    float w[4], denom = 0.f;
    #pragma unroll
    for (int s = 0; s < 4; ++s) {
        w[s] = __expf(m[s] - mg);
        denom += l[s] * w[s];
    }
    const float inv = 1.f / denom;
    float acc[16] = {};
    #pragma unroll
    for (int s = 0; s < 4; ++s) {
        const unsigned short* p = Op16 + ((size_t)(s * 4 + h) * 8192 + q) * 64 + c * 16;
        short8 v0 = *(const short8*)(p);
        short8 v1 = *(const short8*)(p + 8);
        #pragma unroll
        for (int i = 0; i < 8; ++i) {
            acc[i]     += w[s] * bf2f((unsigned short)v0[i]);
            acc[i + 8] += w[s] * bf2f((unsigned short)v1[i]);
        }
    }
    float* dst = aO + (size_t)q * 256 + h * 64 + c * 16;
    #pragma unroll
    for (int i = 0; i < 4; ++i) {
        float4 r = { acc[4*i] * inv, acc[4*i+1] * inv, acc[4*i+2] * inv, acc[4*i+3] * inv };
        *(float4*)(dst + i * 4) = r;
    }
}

// ---------------- launch ----------------
extern "C" void kernel_launch(void* const* d_in, const int* in_sizes, int n_in,
                              void* d_out, int out_size, void* d_ws, size_t ws_size,
                              hipStream_t stream)
{
    const float* x     = (const float*)d_in[0];
    const int*   ei    = (const int*)  d_in[1];
    const float* W_in  = (const float*)d_in[2];
    const float* b_in  = (const float*)d_in[3];
    const float* plas  = (const float*)d_in[4];
    const float* syn   = (const float*)d_in[5];
    const float* inpw  = (const float*)d_in[6];
    const float* inpb  = (const float*)d_in[7];
    const float* outpw = (const float*)d_in[8];
    const float* outpb = (const float*)d_in[9];
    const float* Wout  = (const float*)d_in[10];
    const float* bout  = (const float*)d_in[11];
    float* out = (float*)d_out;

    char* ws = (char*)d_ws;
    // layout (58.1 MiB):
    //  0..8MB   : h (GNN) -> Kc0(0..4), Kc1(4..8) (attn) -> aO (combine out)
    //  8..16MB  : h2 (GNN) -> Kc2(8..12), Vt0(12..16)
    // 16..40MB  : qkv (live through attn)
    // 40..56MB  : Op16 (bf16, 4 splits x 4 heads x 8192 x 64) -> tmp@48MB after combine
    // 56MB..    : rowp, curs, esrc (-> Ml during attn)
    float* h    = (float*)(ws + 0);
    float* h2   = (float*)(ws + (8u  << 20));
    float* qkv  = (float*)(ws + (16u << 20));
    float* aO   = (float*)(ws + 0);
    float* tmp  = (float*)(ws + (48u << 20));
    unsigned short* Op16 = (unsigned short*)(ws + (40u << 20));
    unsigned short* Kc0 = (unsigned short*)(ws + 0);
    unsigned short* Kc1 = (unsigned short*)(ws + (4u  << 20));
    unsigned short* Kc2 = (unsigned short*)(ws + (8u  << 20));
    unsigned short* Vt0 = (unsigned short*)(ws + (12u << 20));
    int*   rowp = (int*)(ws + (56u << 20));
    int*   curs = (int*)(ws + (56u << 20) + 40960);
    int*   esrc = (int*)(ws + (56u << 20) + 81920);
    float* Ml   = (float*)(ws + (56u << 20) + 81920);   // reuses esrc (dead after aggregates)

    // CSR build
    hipMemsetAsync(curs, 0, N_NODES * sizeof(int), stream);
    hist_kernel<<<NEDGE / 256, 256, 0, stream>>>(ei, curs);
    scan_kernel<<<1, 1024, 0, stream>>>(curs, rowp, curs);
    scatter_kernel<<<NEDGE / 256, 256, 0, stream>>>(ei, curs, esrc);

    // input projection (M=8192, N=256, K=128)
    gemm_bias_kernel<<<dim3(N_NODES / 128, HID / 64), 256, 0, stream>>>(
        x, W_in, b_in, h, N_NODES, HID, IND);

    // 3 GNN layers
    aggregate_kernel<<<N_NODES, 256, 0, stream>>>(h,  h2, rowp, esrc, plas, syn, 0);
    aggregate_kernel<<<N_NODES, 256, 0, stream>>>(h2, h,  rowp, esrc, plas, syn, 1);
    aggregate_kernel<<<N_NODES, 256, 0, stream>>>(h,  h2, rowp, esrc, plas, syn, 2);

    // qkv projection (N=768)
    gemm_bias_kernel<<<dim3(N_NODES / 128, 768 / 64), 256, 0, stream>>>(
        h2, inpw, inpb, qkv, N_NODES, 768, HID);

    // split pre-pass
    split_kernel<<<dim3(N_NODES / 64, NHEAD), 256, 0, stream>>>(
        qkv, Kc0, Kc1, Kc2, Vt0);

    // MFMA attention: 256 q/block, split-K x4, 512 blocks (2 blocks/CU)
    attn_mfma_kernel<<<dim3(N_NODES / 256, NHEAD, 4), 256, 0, stream>>>(
        qkv, Kc0, Kc1, Kc2, Vt0, Op16, Ml);

    // combine quarters
    combine_kernel<<<512, 256, 0, stream>>>(Op16, Ml, aO);

    // output projections
    gemm_bias_kernel<<<dim3(N_NODES / 128, HID / 64), 256, 0, stream>>>(
        aO, outpw, outpb, tmp, N_NODES, HID, HID);
    gemm_bias_kernel<<<dim3(N_NODES / 128, OUTD / 64), 256, 0, stream>>>(
        tmp, Wout, bout, out, N_NODES, OUTD, HID);
}